// Round 7
// baseline (206.452 us; speedup 1.0000x reference)
//
#include <hip/hip_runtime.h>

typedef _Float16 half_t;
typedef _Float16 half2_t __attribute__((ext_vector_type(2)));
typedef _Float16 half4_t __attribute__((ext_vector_type(4)));
typedef _Float16 half8_t __attribute__((ext_vector_type(8)));
typedef float floatx4 __attribute__((ext_vector_type(4)));
typedef float floatx16 __attribute__((ext_vector_type(16)));

#define NE 512
#define NS 16
#define NBATCH 2048
#define NK 64
#define AS 552  // LDS row stride (halves)

// gelu(x) = 0.5 x (1 + erf(x/sqrt2)); erf via A&S 7.1.26 (|err|<=1.5e-7), branch-free.
__device__ __forceinline__ float gelu_erf(float x) {
    float z = x * 0.70710678118654752440f;
    float az2 = z * z;
    float az = __builtin_fabsf(z);
    float t = __builtin_amdgcn_rcpf(__builtin_fmaf(0.3275911f, az, 1.0f));
    float p = __builtin_fmaf(1.061405429f, t, -1.453152027f);
    p = __builtin_fmaf(p, t, 1.421413741f);
    p = __builtin_fmaf(p, t, -0.284496736f);
    p = __builtin_fmaf(p, t, 0.254829592f);
    p = p * t;
    float e = __expf(-az2);
    float erfa = __builtin_fmaf(-p, e, 1.0f);
    unsigned int u = __float_as_uint(erfa) ^ (__float_as_uint(z) & 0x80000000u);
    return 0.5f * x * (1.0f + __uint_as_float(u));
}

__device__ __forceinline__ half4_t cvt4(float4 v) {
    return (half4_t){(half_t)v.x, (half_t)v.y, (half_t)v.z, (half_t)v.w};
}

// packed 32-lane column reduction of 16 values: returns full col-sum of
// x[ln&15] at each lane (reduction over the 32-lane half).
__device__ __forceinline__ float colreduce16(const float (&x)[16], int lnb) {
    float y[8];
#pragma unroll
    for (int i = 0; i < 8; ++i) {
        float keep = (lnb & 1) ? x[2 * i + 1] : x[2 * i];
        float send = (lnb & 1) ? x[2 * i] : x[2 * i + 1];
        y[i] = keep + __shfl_xor(send, 1, 64);
    }
    float z[4];
#pragma unroll
    for (int i = 0; i < 4; ++i) {
        float keep = (lnb & 2) ? y[2 * i + 1] : y[2 * i];
        float send = (lnb & 2) ? y[2 * i] : y[2 * i + 1];
        z[i] = keep + __shfl_xor(send, 2, 64);
    }
    float u[2];
#pragma unroll
    for (int i = 0; i < 2; ++i) {
        float keep = (lnb & 4) ? z[2 * i + 1] : z[2 * i];
        float send = (lnb & 4) ? z[2 * i] : z[2 * i + 1];
        u[i] = keep + __shfl_xor(send, 4, 64);
    }
    float keep = (lnb & 8) ? u[1] : u[0];
    float send = (lnb & 8) ? u[0] : u[1];
    float v = keep + __shfl_xor(send, 8, 64);
    v += __shfl_xor(v, 16, 64);
    return v;
}

// epilogue helper: gelu+scale one 32-row acc tile, col-reduce, store partials.
__device__ __forceinline__ void epi_one(const floatx16& acc, float qv, float w2,
                                        int rowofs, int cg, int ln, int hi,
                                        float (*Llds)[17]) {
    float g[16];
#pragma unroll
    for (int r = 0; r < 16; ++r) g[r] = gelu_erf(acc[r] + qv) * w2;
    float rr = colreduce16(g, ln);
    if (ln < 16) {
        int row = (ln & 3) + 8 * (ln >> 2) + 4 * hi;
        Llds[rowofs + row][cg] = rr;
    }
}

// ---------------------------------------------------------------------------
// pack bodies (device): 16x16x32 layout dst[(t*512+n)*32+kk] and 32x32x16
// layout dst[(t*512+n)*16+kk]. Shared tile passed in (max 32*68 halves).
__device__ void pack_w_body(const float* __restrict__ src, half_t* __restrict__ dst,
                            int Ksrc, int t, int nb0, half_t* tile) {
    int tid = threadIdx.x;
#pragma unroll
    for (int i = 0; i < 8; ++i) {
        int idx = tid + i * 256;
        int kk = idx >> 6, np = idx & 63;
        int k = t * 32 + kk;
        float v = (k < Ksrc) ? src[(size_t)k * NE + nb0 + np] : 0.0f;
        tile[kk * 68 + np] = (half_t)v;
    }
    __syncthreads();
#pragma unroll
    for (int i = 0; i < 8; ++i) {
        int idx = tid + i * 256;
        int np = idx >> 5, kk = idx & 31;
        dst[((size_t)t * NE + nb0 + np) * 32 + kk] = tile[kk * 68 + np];
    }
}

__device__ void pack_w32_body(const float* __restrict__ src, half_t* __restrict__ dst,
                              int Ksrc, int t, int nb0, half_t* tile) {
    int tid = threadIdx.x;
#pragma unroll
    for (int i = 0; i < 4; ++i) {
        int idx = tid + i * 256;
        int kk = idx >> 6, n = idx & 63;
        int k = t * 16 + kk;
        float v = (k < Ksrc) ? src[(size_t)k * NE + nb0 + n] : 0.0f;
        tile[kk * 68 + n] = (half_t)v;
    }
    __syncthreads();
    int n = threadIdx.x >> 2, q = threadIdx.x & 3;
    half4_t h = {tile[(q * 4) * 68 + n], tile[(q * 4 + 1) * 68 + n],
                 tile[(q * 4 + 2) * 68 + n], tile[(q * 4 + 3) * 68 + n]};
    *(half4_t*)&dst[((size_t)t * NE + nb0 + n) * 16 + q * 4] = h;
}

// pack_all: one launch does all four weight packs. Block ranges:
// [0,256) Wq | [256,520) Wns (32x32 layout) | [520,656) Wp1 | [656,784) Wp2.
__global__ __launch_bounds__(256) void pack_all(
    const float* __restrict__ sw1, const float* __restrict__ pw1,
    const float* __restrict__ pw2, half_t* __restrict__ Wq,
    half_t* __restrict__ Wns, half_t* __restrict__ Wp1, half_t* __restrict__ Wp2) {
    __shared__ half_t tile[32 * 68];
    int bx = blockIdx.x;
    if (bx < 256) {
        pack_w_body(sw1, Wq, 1024, bx >> 3, (bx & 7) * 64, tile);
    } else if (bx < 520) {
        int b2 = bx - 256;
        pack_w32_body(sw1 + (size_t)1024 * NE, Wns, 528, b2 >> 3, (b2 & 7) * 64, tile);
    } else if (bx < 656) {
        int b3 = bx - 520;
        pack_w_body(pw1, Wp1, 528, b3 >> 3, (b3 & 7) * 64, tile);
    } else {
        int b4 = bx - 656;
        pack_w_body(pw2, Wp2, 512, b4 >> 3, (b4 & 7) * 64, tile);
    }
}

// ---------------------------------------------------------------------------
// qc_kernel: qc[b,n] = q[b]@sw1[0:512] + c[b]@sw1[512:1024] + sb1[n].
// grid = 256: bx>>1 = 16-row group, bx&1 = 256-col half (all CUs busy).
__global__ __launch_bounds__(512) void qc_kernel(const float* __restrict__ q,
                                                 const float* __restrict__ c,
                                                 const half_t* __restrict__ Wq,
                                                 const float* __restrict__ sb1,
                                                 float* __restrict__ qcb) {
    constexpr int AS1 = 1032;
    __shared__ __align__(16) half_t A1[16 * AS1];
    int b0 = (blockIdx.x >> 1) * 16;
    int nh = (blockIdx.x & 1) * 256;
    int tid = threadIdx.x;
#pragma unroll
    for (int i = 0; i < 8; ++i) {
        int f = tid + i * 512;
        int row = f >> 8;
        int c4 = f & 255;
        const float* srcp = (c4 < 128) ? (q + (size_t)(b0 + row) * NE + c4 * 4)
                                       : (c + (size_t)(b0 + row) * NE + (c4 - 128) * 4);
        float4 v = *(const float4*)srcp;
        *(half4_t*)&A1[row * AS1 + c4 * 4] = cvt4(v);
    }
    __syncthreads();
    int w = tid >> 6, l = tid & 63, lg = l >> 4, ln = l & 15;
    floatx4 acc[2] = { {0,0,0,0}, {0,0,0,0} };
    for (int t = 0; t < 32; ++t) {
        half8_t a = *(const half8_t*)&A1[ln * AS1 + t * 32 + 8 * lg];
#pragma unroll
        for (int ni = 0; ni < 2; ++ni) {
            int n = nh + w * 32 + ni * 16 + ln;
            half8_t bf = *(const half8_t*)(Wq + ((size_t)t * NE + n) * 32 + 8 * lg);
            acc[ni] = __builtin_amdgcn_mfma_f32_16x16x32_f16(a, bf, acc[ni], 0, 0, 0);
        }
    }
#pragma unroll
    for (int ni = 0; ni < 2; ++ni) {
        int col = nh + w * 32 + ni * 16 + ln;
        float bias = sb1[col];
#pragma unroll
        for (int r = 0; r < 4; ++r) {
            int row = 4 * lg + r;
            qcb[(size_t)(b0 + row) * NE + col] = acc[ni][r] + bias;
        }
    }
}

// ---------------------------------------------------------------------------
// main_kernel v8: BATCH-PAIR M=128. Block = 2 batch elements; 1024 threads =
// 16 waves; A-tile 128x552 f16 = 141 KB LDS -> 1 block/CU (16 waves = 4/SIMD,
// same TLP as v1/v7). Each wave owns 32 N-cols over ALL 128 M-rows: per
// K-step 1 B-frag feeds 4 MFMA (v1: 1 B per 2 MFMA) -> B-load instrs + L2
// weight traffic HALVE per batch; single N-pass (no pass-2 machinery);
// barrier phases per batch halve (5 per pair). acc = 4x floatx16 = 64 regs;
// B = rolling 4-slot (slot = t&3 static; invariant: bf[t&3] holds B(t), refill
// puts t+4 in the same slot); A staged 1 chunk ahead (4 float4). Peak regs
// ~116 <= 128 (__launch_bounds__(1024,4)). Keeps v7's setprio + sim-prefetch.
// WRITE_SIZE is the spill gate (~2.7 MB clean). Neighbor rows of the pair are
// CONTIGUOUS (nb0 + r*NE, r in [0,128)), same for stats -- single base ptr.
__global__ __launch_bounds__(1024, 4) void main_kernel(
    const float* __restrict__ neighbors, const float* __restrict__ stats,
    const half_t* __restrict__ Wns, const float* __restrict__ qcb,
    const float* __restrict__ sw2, const float* __restrict__ sb2,
    const float* __restrict__ alpha, float* __restrict__ attn_out,
    half_t* __restrict__ mixed) {
    __shared__ __align__(16) half_t A[128 * AS];  // 141312 B
    __shared__ float Llds[128][17];               // 8704 B
    __shared__ float attn_s[16][64];              // 4096 B  (total 154112)

    int b0 = blockIdx.x * 2;
    int tid = threadIdx.x;
    const float* nb0 = neighbors + (size_t)b0 * NK * NE;  // rows 0..127 of pair
    const float* st0 = stats + (size_t)b0 * NK * NS;      // rows 0..127 of pair

    int r0 = tid >> 5;     // 0..31 (staging rows r0 + 32i)
    int c4 = tid & 31;     // float4-col within 128-col chunk
    int w = tid >> 6;      // wave 0..15; waves 0-7 = batch 0, 8-15 = batch 1
    int l = tid & 63, ln = l & 31, hi = l >> 5;
    const half_t* Abase = A + ln * AS + 8 * hi;
    const half_t* Wb = Wns + ((size_t)(w * 32 + ln)) * 16 + 8 * hi;  // + t*8192

    float4 s0, s1, s2, s3, sst;
    float qv0, qv1, w2s;
    half8_t bf0, bf1, bf2, bf3;

    // ---- prologue: stage chunk 0; issue chunk 1; B t=0..3; scalars; sim ----
    {
        float4 p0 = *(const float4*)(nb0 + (size_t)(r0) * NE + 4 * c4);
        float4 p1 = *(const float4*)(nb0 + (size_t)(r0 + 32) * NE + 4 * c4);
        float4 p2 = *(const float4*)(nb0 + (size_t)(r0 + 64) * NE + 4 * c4);
        float4 p3 = *(const float4*)(nb0 + (size_t)(r0 + 96) * NE + 4 * c4);
        qv0 = qcb[(size_t)b0 * NE + w * 32 + ln];
        qv1 = qcb[(size_t)(b0 + 1) * NE + w * 32 + ln];
        w2s = sw2[w * 32 + ln];
        bf0 = *(const half8_t*)(Wb);
        bf1 = *(const half8_t*)(Wb + 8192);
        bf2 = *(const half8_t*)(Wb + 2 * 8192);
        bf3 = *(const half8_t*)(Wb + 3 * 8192);
        __builtin_amdgcn_sched_barrier(0);
        *(half4_t*)&A[(r0) * AS + 4 * c4] = cvt4(p0);
        *(half4_t*)&A[(r0 + 32) * AS + 4 * c4] = cvt4(p1);
        *(half4_t*)&A[(r0 + 64) * AS + 4 * c4] = cvt4(p2);
        *(half4_t*)&A[(r0 + 96) * AS + 4 * c4] = cvt4(p3);
        __builtin_amdgcn_sched_barrier(0);
        s0 = *(const float4*)(nb0 + (size_t)(r0) * NE + 128 + 4 * c4);
        s1 = *(const float4*)(nb0 + (size_t)(r0 + 32) * NE + 128 + 4 * c4);
        s2 = *(const float4*)(nb0 + (size_t)(r0 + 64) * NE + 128 + 4 * c4);
        s3 = *(const float4*)(nb0 + (size_t)(r0 + 96) * NE + 128 + 4 * c4);
        // softmax sim column (both batches contiguous) -> Llds pad col
        if (tid < 128) Llds[tid][16] = st0[tid * NS + (NS - 1)];
    }
    asm volatile("s_waitcnt lgkmcnt(0)" ::: "memory");
    __builtin_amdgcn_sched_barrier(0);
    __builtin_amdgcn_s_barrier();
    __builtin_amdgcn_sched_barrier(0);

    floatx16 acc0 = {0,0,0,0,0,0,0,0,0,0,0,0,0,0,0,0};
    floatx16 acc1 = {0,0,0,0,0,0,0,0,0,0,0,0,0,0,0,0};
    floatx16 acc2 = {0,0,0,0,0,0,0,0,0,0,0,0,0,0,0,0};
    floatx16 acc3 = {0,0,0,0,0,0,0,0,0,0,0,0,0,0,0,0};

    // ---- chunks 0..2: issue next; 8 K-steps x 4 MFMA; write; barrier ----
#pragma unroll 1
    for (int ch = 0; ch < 3; ++ch) {
        float4 n0, n1, n2, n3;
        if (ch < 2) {
            int nc = (ch + 2) * 128;
            n0 = *(const float4*)(nb0 + (size_t)(r0) * NE + nc + 4 * c4);
            n1 = *(const float4*)(nb0 + (size_t)(r0 + 32) * NE + nc + 4 * c4);
            n2 = *(const float4*)(nb0 + (size_t)(r0 + 64) * NE + nc + 4 * c4);
            n3 = *(const float4*)(nb0 + (size_t)(r0 + 96) * NE + nc + 4 * c4);
        } else {
            // issue stats (128 rows x 16 f32 = 512 float4, contiguous pair)
            if (tid < 512)
                sst = *(const float4*)(st0 + (tid >> 2) * NS + (tid & 3) * 4);
        }
        __builtin_amdgcn_sched_barrier(0);
        __builtin_amdgcn_s_setprio(1);
#pragma unroll
        for (int s8 = 0; s8 < 8; ++s8) {
            int t = ch * 8 + s8;
            int col = t * 16;
            half8_t bc;
            if ((s8 & 3) == 0) bc = bf0;
            else if ((s8 & 3) == 1) bc = bf1;
            else if ((s8 & 3) == 2) bc = bf2;
            else bc = bf3;
            half8_t a0 = *(const half8_t*)&Abase[col];
            half8_t a1 = *(const half8_t*)&Abase[32 * AS + col];
            half8_t a2 = *(const half8_t*)&Abase[64 * AS + col];
            half8_t a3 = *(const half8_t*)&Abase[96 * AS + col];
            acc0 = __builtin_amdgcn_mfma_f32_32x32x16_f16(a0, bc, acc0, 0, 0, 0);
            acc1 = __builtin_amdgcn_mfma_f32_32x32x16_f16(a1, bc, acc1, 0, 0, 0);
            acc2 = __builtin_amdgcn_mfma_f32_32x32x16_f16(a2, bc, acc2, 0, 0, 0);
            acc3 = __builtin_amdgcn_mfma_f32_32x32x16_f16(a3, bc, acc3, 0, 0, 0);
            // refill same slot with t+4 (ch<3: t+4 <= 27 always valid)
            half8_t nb8 = *(const half8_t*)(Wb + (size_t)(t + 4) * 8192);
            if ((s8 & 3) == 0) bf0 = nb8;
            else if ((s8 & 3) == 1) bf1 = nb8;
            else if ((s8 & 3) == 2) bf2 = nb8;
            else bf3 = nb8;
        }
        __builtin_amdgcn_s_setprio(0);
        __builtin_amdgcn_sched_barrier(0);
        {
            int cb = (ch + 1) * 128;
            *(half4_t*)&A[(r0) * AS + cb + 4 * c4] = cvt4(s0);
            *(half4_t*)&A[(r0 + 32) * AS + cb + 4 * c4] = cvt4(s1);
            *(half4_t*)&A[(r0 + 64) * AS + cb + 4 * c4] = cvt4(s2);
            *(half4_t*)&A[(r0 + 96) * AS + cb + 4 * c4] = cvt4(s3);
            s0 = n0; s1 = n1; s2 = n2; s3 = n3;
        }
        asm volatile("s_waitcnt lgkmcnt(0)" ::: "memory");
        __builtin_amdgcn_sched_barrier(0);
        __builtin_amdgcn_s_barrier();
        __builtin_amdgcn_sched_barrier(0);
    }

    // ---- chunk 3 (t = 24..31): refill only while t+4 <= 32; stats write ----
    {
        __builtin_amdgcn_s_setprio(1);
#pragma unroll
        for (int s8 = 0; s8 < 8; ++s8) {
            int t = 24 + s8;
            int col = t * 16;
            half8_t bc;
            if ((s8 & 3) == 0) bc = bf0;
            else if ((s8 & 3) == 1) bc = bf1;
            else if ((s8 & 3) == 2) bc = bf2;
            else bc = bf3;
            half8_t a0 = *(const half8_t*)&Abase[col];
            half8_t a1 = *(const half8_t*)&Abase[32 * AS + col];
            half8_t a2 = *(const half8_t*)&Abase[64 * AS + col];
            half8_t a3 = *(const half8_t*)&Abase[96 * AS + col];
            acc0 = __builtin_amdgcn_mfma_f32_32x32x16_f16(a0, bc, acc0, 0, 0, 0);
            acc1 = __builtin_amdgcn_mfma_f32_32x32x16_f16(a1, bc, acc1, 0, 0, 0);
            acc2 = __builtin_amdgcn_mfma_f32_32x32x16_f16(a2, bc, acc2, 0, 0, 0);
            acc3 = __builtin_amdgcn_mfma_f32_32x32x16_f16(a3, bc, acc3, 0, 0, 0);
            if (s8 <= 4) {  // t+4 = 28..32 (static condition)
                half8_t nb8 = *(const half8_t*)(Wb + (size_t)(t + 4) * 8192);
                if ((s8 & 3) == 0) bf0 = nb8;
                else if ((s8 & 3) == 1) bf1 = nb8;
                else if ((s8 & 3) == 2) bf2 = nb8;
                else bf3 = nb8;
            }
        }
        __builtin_amdgcn_s_setprio(0);
        __builtin_amdgcn_sched_barrier(0);
        if (tid < 512)
            *(half4_t*)&A[(tid >> 2) * AS + 512 + (tid & 3) * 4] = cvt4(sst);
        asm volatile("s_waitcnt lgkmcnt(0)" ::: "memory");
        __builtin_amdgcn_sched_barrier(0);
        __builtin_amdgcn_s_barrier();
        __builtin_amdgcn_sched_barrier(0);
    }
    // K-tail t=32 (stats cols 512..527): slot 32&3=0 -> bf0 (refilled s8==4)
    {
        half8_t a0 = *(const half8_t*)&Abase[512];
        half8_t a1 = *(const half8_t*)&Abase[32 * AS + 512];
        half8_t a2 = *(const half8_t*)&Abase[64 * AS + 512];
        half8_t a3 = *(const half8_t*)&Abase[96 * AS + 512];
        __builtin_amdgcn_s_setprio(1);
        acc0 = __builtin_amdgcn_mfma_f32_32x32x16_f16(a0, bf0, acc0, 0, 0, 0);
        acc1 = __builtin_amdgcn_mfma_f32_32x32x16_f16(a1, bf0, acc1, 0, 0, 0);
        acc2 = __builtin_amdgcn_mfma_f32_32x32x16_f16(a2, bf0, acc2, 0, 0, 0);
        acc3 = __builtin_amdgcn_mfma_f32_32x32x16_f16(a3, bf0, acc3, 0, 0, 0);
        __builtin_amdgcn_s_setprio(0);
    }

    // ---- epilogue: 4 tiles (rows 0-31,32-63 = batch0; 64-95,96-127 = b1) ----
    epi_one(acc0, qv0, w2s, 0,  w, ln, hi, Llds);
    epi_one(acc1, qv0, w2s, 32, w, ln, hi, Llds);
    epi_one(acc2, qv1, w2s, 64, w, ln, hi, Llds);
    epi_one(acc3, qv1, w2s, 96, w, ln, hi, Llds);
    __syncthreads();   // Llds is cross-wave: barrier required

    // ---- softmax: waves 0-7 batch0, 8-15 batch1 (redundant x8 each) ----
    {
        int g = w >> 3;           // batch within pair
        int k = l;                // lane owns k
        float lsum = 0.0f;
#pragma unroll
        for (int j = 0; j < 16; ++j) lsum += Llds[g * 64 + k][j];
        float sim = Llds[g * 64 + k][16];   // prefetched at prologue
        float logit = lsum + sb2[0] + alpha[0] * sim;
        float mx = logit;
#pragma unroll
        for (int m = 1; m < 64; m <<= 1) mx = fmaxf(mx, __shfl_xor(mx, m, 64));
        float e = __expf(logit - mx);
        float s = e;
#pragma unroll
        for (int m = 1; m < 64; m <<= 1) s += __shfl_xor(s, m, 64);
        float at = e / s;
        attn_s[w][k] = at;                 // own wave's copy: DS in-order
        if (w == 0) attn_out[(size_t)b0 * NK + k] = at;
        if (w == 8) attn_out[(size_t)(b0 + 1) * NK + k] = at;
    }
    // NO barrier: each wave reads only its own attn_s[w] copy below.

    // ---- mix from LDS: tid<512 -> batch0 col tid; tid>=512 -> batch1 ----
    {
        int g = tid >> 9;          // == w>>3 for this thread
        int c0 = tid & 511;        // col 0..511
        float m0 = 0.0f;
#pragma unroll 8
        for (int k = 0; k < NK; ++k) {
            float aw = attn_s[w][k];
            m0 += aw * (float)A[(g * 64 + k) * AS + c0];
        }
        mixed[(size_t)(b0 + g) * AS + c0] = (half_t)m0;
        // stats cols 512..527: tid<16 (wave 0, batch0) / tid in [512,528) (wave 8, b1)
        if (c0 < 16) {
            int cs = 512 + c0;
            float n0 = 0.0f;
#pragma unroll 8
            for (int k = 0; k < NK; ++k)
                n0 += attn_s[w][k] * (float)A[(g * 64 + k) * AS + cs];
            mixed[(size_t)(b0 + g) * AS + cs] = (half_t)n0;
        } else if (c0 < 28) {
            int z = c0 - 16;  // zero cols 528..551 (12 threads x half2 per batch)
            *(half2_t*)&mixed[(size_t)(b0 + g) * AS + 528 + 2 * z] = (half2_t){};
        }
    }
}

// ---------------------------------------------------------------------------
// proj_kernel: out = gelu(mixed@pw1 + pb1) @ pw2 + pb2, both layers fused.
// 1024 threads = 16 waves (wave owns 32 cols) for better latency hiding.
__global__ __launch_bounds__(1024) void proj_kernel(
    const half_t* __restrict__ mixedp, const half_t* __restrict__ Wp1,
    const half_t* __restrict__ Wp2, const float* __restrict__ pb1,
    const float* __restrict__ pb2, float* __restrict__ out) {
    constexpr int AS3 = AS;
    __shared__ __align__(16) half_t A1[16 * AS3];
    int b0 = blockIdx.x * 16;
    int tid = threadIdx.x;
    const uint4* src = (const uint4*)(mixedp + (size_t)b0 * AS3);
    for (int i = tid; i < 1104; i += 1024) ((uint4*)A1)[i] = src[i];
    __syncthreads();

    int w = tid >> 6, l = tid & 63, lg = l >> 4, ln = l & 15;
    floatx4 acc[2] = { {0,0,0,0}, {0,0,0,0} };
    for (int t = 0; t < 17; ++t) {
        half8_t a = *(const half8_t*)&A1[ln * AS3 + t * 32 + 8 * lg];
#pragma unroll
        for (int ni = 0; ni < 2; ++ni) {
            int n = w * 32 + ni * 16 + ln;
            half8_t bf = *(const half8_t*)(Wp1 + ((size_t)t * NE + n) * 32 + 8 * lg);
            acc[ni] = __builtin_amdgcn_mfma_f32_16x16x32_f16(a, bf, acc[ni], 0, 0, 0);
        }
    }
    __syncthreads();
#pragma unroll
    for (int ni = 0; ni < 2; ++ni) {
        int col = w * 32 + ni * 16 + ln;
        float bias = pb1[col];
#pragma unroll
        for (int r = 0; r < 4; ++r) {
            int row = 4 * lg + r;
            A1[row * AS3 + col] = (half_t)gelu_erf(acc[ni][r] + bias);
        }
    }
    __syncthreads();
    floatx4 acc2[2] = { {0,0,0,0}, {0,0,0,0} };
    for (int t = 0; t < 16; ++t) {
        half8_t a = *(const half8_t*)&A1[ln * AS3 + t * 32 + 8 * lg];
#pragma unroll
        for (int ni = 0; ni < 2; ++ni) {
            int n = w * 32 + ni * 16 + ln;
            half8_t bf = *(const half8_t*)(Wp2 + ((size_t)t * NE + n) * 32 + 8 * lg);
            acc2[ni] = __builtin_amdgcn_mfma_f32_16x16x32_f16(a, bf, acc2[ni], 0, 0, 0);
        }
    }
#pragma unroll
    for (int ni = 0; ni < 2; ++ni) {
        int col = w * 32 + ni * 16 + ln;
        float bias = pb2[col];
#pragma unroll
        for (int r = 0; r < 4; ++r)
            out[(size_t)(b0 + 4 * lg + r) * NE + col] = acc2[ni][r] + bias;
    }
}

// ---------------------------------------------------------------------------
extern "C" void kernel_launch(void* const* d_in, const int* in_sizes, int n_in,
                              void* d_out, int out_size, void* d_ws, size_t ws_size,
                              hipStream_t stream) {
    (void)in_sizes; (void)n_in; (void)out_size; (void)ws_size;
    const float* q     = (const float*)d_in[0];
    const float* c     = (const float*)d_in[1];
    const float* nb    = (const float*)d_in[2];
    const float* st    = (const float*)d_in[3];
    const float* sw1   = (const float*)d_in[4];
    const float* sb1   = (const float*)d_in[5];
    const float* sw2   = (const float*)d_in[6];
    const float* sb2   = (const float*)d_in[7];
    const float* alpha = (const float*)d_in[8];
    const float* pw1   = (const float*)d_in[9];
    const float* pb1   = (const float*)d_in[10];
    const float* pw2   = (const float*)d_in[11];
    const float* pb2   = (const float*)d_in[12];

    char* ws = (char*)d_ws;
    half_t* Wq  = (half_t*)(ws + 0);          // 1024*512*2 = 1048576
    half_t* Wns = (half_t*)(ws + 1048576);    // 33*512*16*2 = 540672
    half_t* Wp1 = (half_t*)(ws + 1605632);    // 544*512*2  = 557056
    half_t* Wp2 = (half_t*)(ws + 2162688);    // 512*512*2  = 524288
    float*  qcb = (float*)(ws + 2686976);     // 2048*512*4 = 4194304
    half_t* mix = (half_t*)(ws + 6881280);    // 2048*552*2 = 2260992

    float* outp  = (float*)d_out;
    float* attnp = outp + (size_t)NBATCH * NE;

    pack_all<<<784, 256, 0, stream>>>(sw1, pw1, pw2, Wq, Wns, Wp1, Wp2);
    qc_kernel<<<256, 512, 0, stream>>>(q, c, Wq, sb1, qcb);
    main_kernel<<<1024, 1024, 0, stream>>>(nb, st, Wns, qcb, sw2, sb2, alpha, attnp, mix);
    proj_kernel<<<128, 1024, 0, stream>>>(mix, Wp1, Wp2, pb1, pb2, outp);
}

// Round 8
// 177.559 us; speedup vs baseline: 1.1627x; 1.1627x over previous
//
#include <hip/hip_runtime.h>

typedef _Float16 half_t;
typedef _Float16 half2_t __attribute__((ext_vector_type(2)));
typedef _Float16 half4_t __attribute__((ext_vector_type(4)));
typedef _Float16 half8_t __attribute__((ext_vector_type(8)));
typedef float floatx4 __attribute__((ext_vector_type(4)));
typedef float floatx16 __attribute__((ext_vector_type(16)));

#define NE 512
#define NS 16
#define NBATCH 2048
#define NK 64
#define AS 552  // LDS row stride (halves)

// gelu(x) = 0.5 x (1 + erf(x/sqrt2)); erf via A&S 7.1.26 (|err|<=1.5e-7), branch-free.
__device__ __forceinline__ float gelu_erf(float x) {
    float z = x * 0.70710678118654752440f;
    float az2 = z * z;
    float az = __builtin_fabsf(z);
    float t = __builtin_amdgcn_rcpf(__builtin_fmaf(0.3275911f, az, 1.0f));
    float p = __builtin_fmaf(1.061405429f, t, -1.453152027f);
    p = __builtin_fmaf(p, t, 1.421413741f);
    p = __builtin_fmaf(p, t, -0.284496736f);
    p = __builtin_fmaf(p, t, 0.254829592f);
    p = p * t;
    float e = __expf(-az2);
    float erfa = __builtin_fmaf(-p, e, 1.0f);
    unsigned int u = __float_as_uint(erfa) ^ (__float_as_uint(z) & 0x80000000u);
    return 0.5f * x * (1.0f + __uint_as_float(u));
}

__device__ __forceinline__ half4_t cvt4(float4 v) {
    return (half4_t){(half_t)v.x, (half_t)v.y, (half_t)v.z, (half_t)v.w};
}

// packed 32-lane column reduction of 16 values: returns full col-sum of
// x[ln&15] at each lane (reduction over the 32-lane half).
__device__ __forceinline__ float colreduce16(const float (&x)[16], int lnb) {
    float y[8];
#pragma unroll
    for (int i = 0; i < 8; ++i) {
        float keep = (lnb & 1) ? x[2 * i + 1] : x[2 * i];
        float send = (lnb & 1) ? x[2 * i] : x[2 * i + 1];
        y[i] = keep + __shfl_xor(send, 1, 64);
    }
    float z[4];
#pragma unroll
    for (int i = 0; i < 4; ++i) {
        float keep = (lnb & 2) ? y[2 * i + 1] : y[2 * i];
        float send = (lnb & 2) ? y[2 * i] : y[2 * i + 1];
        z[i] = keep + __shfl_xor(send, 2, 64);
    }
    float u[2];
#pragma unroll
    for (int i = 0; i < 2; ++i) {
        float keep = (lnb & 4) ? z[2 * i + 1] : z[2 * i];
        float send = (lnb & 4) ? z[2 * i] : z[2 * i + 1];
        u[i] = keep + __shfl_xor(send, 4, 64);
    }
    float keep = (lnb & 8) ? u[1] : u[0];
    float send = (lnb & 8) ? u[0] : u[1];
    float v = keep + __shfl_xor(send, 8, 64);
    v += __shfl_xor(v, 16, 64);
    return v;
}

// ---------------------------------------------------------------------------
// pack bodies (device): 16x16x32 layout dst[(t*512+n)*32+kk] and 32x32x16
// layout dst[(t*512+n)*16+kk]. Shared tile passed in (max 32*68 halves).
__device__ void pack_w_body(const float* __restrict__ src, half_t* __restrict__ dst,
                            int Ksrc, int t, int nb0, half_t* tile) {
    int tid = threadIdx.x;
#pragma unroll
    for (int i = 0; i < 8; ++i) {
        int idx = tid + i * 256;
        int kk = idx >> 6, np = idx & 63;
        int k = t * 32 + kk;
        float v = (k < Ksrc) ? src[(size_t)k * NE + nb0 + np] : 0.0f;
        tile[kk * 68 + np] = (half_t)v;
    }
    __syncthreads();
#pragma unroll
    for (int i = 0; i < 8; ++i) {
        int idx = tid + i * 256;
        int np = idx >> 5, kk = idx & 31;
        dst[((size_t)t * NE + nb0 + np) * 32 + kk] = tile[kk * 68 + np];
    }
}

__device__ void pack_w32_body(const float* __restrict__ src, half_t* __restrict__ dst,
                              int Ksrc, int t, int nb0, half_t* tile) {
    int tid = threadIdx.x;
#pragma unroll
    for (int i = 0; i < 4; ++i) {
        int idx = tid + i * 256;
        int kk = idx >> 6, n = idx & 63;
        int k = t * 16 + kk;
        float v = (k < Ksrc) ? src[(size_t)k * NE + nb0 + n] : 0.0f;
        tile[kk * 68 + n] = (half_t)v;
    }
    __syncthreads();
    int n = threadIdx.x >> 2, q = threadIdx.x & 3;
    half4_t h = {tile[(q * 4) * 68 + n], tile[(q * 4 + 1) * 68 + n],
                 tile[(q * 4 + 2) * 68 + n], tile[(q * 4 + 3) * 68 + n]};
    *(half4_t*)&dst[((size_t)t * NE + nb0 + n) * 16 + q * 4] = h;
}

// pack_all: one launch does all four weight packs. Block ranges:
// [0,256) Wq | [256,520) Wns (32x32 layout) | [520,656) Wp1 | [656,784) Wp2.
__global__ __launch_bounds__(256) void pack_all(
    const float* __restrict__ sw1, const float* __restrict__ pw1,
    const float* __restrict__ pw2, half_t* __restrict__ Wq,
    half_t* __restrict__ Wns, half_t* __restrict__ Wp1, half_t* __restrict__ Wp2) {
    __shared__ half_t tile[32 * 68];
    int bx = blockIdx.x;
    if (bx < 256) {
        pack_w_body(sw1, Wq, 1024, bx >> 3, (bx & 7) * 64, tile);
    } else if (bx < 520) {
        int b2 = bx - 256;
        pack_w32_body(sw1 + (size_t)1024 * NE, Wns, 528, b2 >> 3, (b2 & 7) * 64, tile);
    } else if (bx < 656) {
        int b3 = bx - 520;
        pack_w_body(pw1, Wp1, 528, b3 >> 3, (b3 & 7) * 64, tile);
    } else {
        int b4 = bx - 656;
        pack_w_body(pw2, Wp2, 512, b4 >> 3, (b4 & 7) * 64, tile);
    }
}

// ---------------------------------------------------------------------------
// qc_kernel: qc[b,n] = q[b]@sw1[0:512] + c[b]@sw1[512:1024] + sb1[n].
// grid = 256: bx>>1 = 16-row group, bx&1 = 256-col half (all CUs busy).
__global__ __launch_bounds__(512) void qc_kernel(const float* __restrict__ q,
                                                 const float* __restrict__ c,
                                                 const half_t* __restrict__ Wq,
                                                 const float* __restrict__ sb1,
                                                 float* __restrict__ qcb) {
    constexpr int AS1 = 1032;
    __shared__ __align__(16) half_t A1[16 * AS1];
    int b0 = (blockIdx.x >> 1) * 16;
    int nh = (blockIdx.x & 1) * 256;
    int tid = threadIdx.x;
#pragma unroll
    for (int i = 0; i < 8; ++i) {
        int f = tid + i * 512;
        int row = f >> 8;
        int c4 = f & 255;
        const float* srcp = (c4 < 128) ? (q + (size_t)(b0 + row) * NE + c4 * 4)
                                       : (c + (size_t)(b0 + row) * NE + (c4 - 128) * 4);
        float4 v = *(const float4*)srcp;
        *(half4_t*)&A1[row * AS1 + c4 * 4] = cvt4(v);
    }
    __syncthreads();
    int w = tid >> 6, l = tid & 63, lg = l >> 4, ln = l & 15;
    floatx4 acc[2] = { {0,0,0,0}, {0,0,0,0} };
    for (int t = 0; t < 32; ++t) {
        half8_t a = *(const half8_t*)&A1[ln * AS1 + t * 32 + 8 * lg];
#pragma unroll
        for (int ni = 0; ni < 2; ++ni) {
            int n = nh + w * 32 + ni * 16 + ln;
            half8_t bf = *(const half8_t*)(Wq + ((size_t)t * NE + n) * 32 + 8 * lg);
            acc[ni] = __builtin_amdgcn_mfma_f32_16x16x32_f16(a, bf, acc[ni], 0, 0, 0);
        }
    }
#pragma unroll
    for (int ni = 0; ni < 2; ++ni) {
        int col = nh + w * 32 + ni * 16 + ln;
        float bias = sb1[col];
#pragma unroll
        for (int r = 0; r < 4; ++r) {
            int row = 4 * lg + r;
            qcb[(size_t)(b0 + row) * NE + col] = acc[ni][r] + bias;
        }
    }
}

// ---------------------------------------------------------------------------
// main_kernel v9 = v7 (best vertex, 165.4us: full-resident A, 2 blocks/CU,
// 2-pass acc-32, setprio, sim-prefetch; v8 re-proved 1 block/CU loses the
// cross-block overlap) + latency-shadow B prefetch at ZERO peak-reg change:
//  1. pass-1 B half-hoist: bfr[8] -> bfrA[4] (next chunk's first half, issued
//     AFTER the stage-write, BEFORE the barrier -- rides across since our asm
//     waits lgkmcnt only; raw s_barrier doesn't drain vmcnt) + bfrB[4] (loaded
//     at loop top). v4 hoisted all 8 (+32 regs at the peak window -> spill);
//     hoisting 4 keeps the MFMA-window live set identical to v7.
//  2. pass-2 B prefetch 3-deep (pA2/pB2): lead rises ~100->~200cy >= L2
//     latency; +8 regs in a region where the 16 staging regs are dead.
// WRITE_SIZE is the spill gate (~2.7 MB clean).
__global__ __launch_bounds__(512, 4) void main_kernel(
    const float* __restrict__ neighbors, const float* __restrict__ stats,
    const half_t* __restrict__ Wns, const float* __restrict__ qcb,
    const float* __restrict__ sw2, const float* __restrict__ sb2,
    const float* __restrict__ alpha, float* __restrict__ attn_out,
    half_t* __restrict__ mixed) {
    __shared__ __align__(16) half_t A[64 * AS];  // 70656 B
    __shared__ float Llds[64][17];
    __shared__ float attn_s[8][64];              // per-wave copy: no tail barrier

    int b = blockIdx.x;
    int tid = threadIdx.x;
    const float* nb = neighbors + (size_t)b * NK * NE;
    const float* st = stats + (size_t)b * NK * NS;

    int r0 = tid >> 5;     // 0..15 (staging rows r0+16i)
    int c4 = tid & 31;     // float4-col within 128-col chunk
    int w = tid >> 6;      // wave 0..7
    int l = tid & 63, ln = l & 31, hi = l >> 5;
    const half_t* Abase = A + ln * AS + 8 * hi;
    const half_t* Wb = Wns + ((size_t)(w * 32 + ln)) * 16 + 8 * hi;  // + t*8192

    // ---- prologue: stage chunk 0; issue chunk 1; epilogue scalars; sim col;
    //      chunk-0 bfrA (first 4 B tiles -- latency drains under barrier) ----
    float4 s0, s1, s2, s3, sst;
    float qv1, w21, qv2, w22;
    half8_t bfrA0, bfrA1, bfrA2, bfrA3;
    {
        float4 p0 = *(const float4*)(nb + (size_t)(r0) * NE + 4 * c4);
        float4 p1 = *(const float4*)(nb + (size_t)(r0 + 16) * NE + 4 * c4);
        float4 p2 = *(const float4*)(nb + (size_t)(r0 + 32) * NE + 4 * c4);
        float4 p3 = *(const float4*)(nb + (size_t)(r0 + 48) * NE + 4 * c4);
        __builtin_amdgcn_sched_barrier(0);
        s0 = *(const float4*)(nb + (size_t)(r0) * NE + 128 + 4 * c4);
        s1 = *(const float4*)(nb + (size_t)(r0 + 16) * NE + 128 + 4 * c4);
        s2 = *(const float4*)(nb + (size_t)(r0 + 32) * NE + 128 + 4 * c4);
        s3 = *(const float4*)(nb + (size_t)(r0 + 48) * NE + 128 + 4 * c4);
        qv1 = qcb[(size_t)b * NE + w * 32 + ln];
        w21 = sw2[w * 32 + ln];
        qv2 = qcb[(size_t)b * NE + 256 + w * 32 + ln];
        w22 = sw2[256 + w * 32 + ln];
        __builtin_amdgcn_sched_barrier(0);
        *(half4_t*)&A[(r0) * AS + 4 * c4] = cvt4(p0);
        *(half4_t*)&A[(r0 + 16) * AS + 4 * c4] = cvt4(p1);
        *(half4_t*)&A[(r0 + 32) * AS + 4 * c4] = cvt4(p2);
        *(half4_t*)&A[(r0 + 48) * AS + 4 * c4] = cvt4(p3);
        __builtin_amdgcn_sched_barrier(0);
        // chunk-0 first-half B: arrives during the barrier wait below
        bfrA0 = *(const half8_t*)(Wb);
        bfrA1 = *(const half8_t*)(Wb + 8192);
        bfrA2 = *(const half8_t*)(Wb + 2 * 8192);
        bfrA3 = *(const half8_t*)(Wb + 3 * 8192);
        // softmax sim column -> unused Llds pad col (read after final barrier)
        if (tid < 64) Llds[tid][16] = st[tid * NS + (NS - 1)];
    }
    asm volatile("s_waitcnt lgkmcnt(0)" ::: "memory");
    __builtin_amdgcn_sched_barrier(0);
    __builtin_amdgcn_s_barrier();
    __builtin_amdgcn_sched_barrier(0);

    floatx16 acc0 = {0,0,0,0,0,0,0,0,0,0,0,0,0,0,0,0};
    floatx16 acc1 = {0,0,0,0,0,0,0,0,0,0,0,0,0,0,0,0};

    // ---- pass 1, pipelined chunks 0..3 (8 K-steps of 16 each) ----
    half8_t bfa;
#pragma unroll 1
    for (int ch = 0; ch < 4; ++ch) {
        // second-half B of this chunk (used from s8=4, ~4 MFMA after issue)
        half8_t bfrB0 = *(const half8_t*)(Wb + (size_t)(ch * 8 + 4) * 8192);
        half8_t bfrB1 = *(const half8_t*)(Wb + (size_t)(ch * 8 + 5) * 8192);
        half8_t bfrB2 = *(const half8_t*)(Wb + (size_t)(ch * 8 + 6) * 8192);
        half8_t bfrB3 = *(const half8_t*)(Wb + (size_t)(ch * 8 + 7) * 8192);
        float4 n0, n1, n2, n3;
        if (ch < 2) {
            n0 = *(const float4*)(nb + (size_t)(r0) * NE + (ch + 2) * 128 + 4 * c4);
            n1 = *(const float4*)(nb + (size_t)(r0 + 16) * NE + (ch + 2) * 128 + 4 * c4);
            n2 = *(const float4*)(nb + (size_t)(r0 + 32) * NE + (ch + 2) * 128 + 4 * c4);
            n3 = *(const float4*)(nb + (size_t)(r0 + 48) * NE + (ch + 2) * 128 + 4 * c4);
        } else if (ch == 2) {
            if (tid < 256)
                sst = *(const float4*)(st + (tid >> 2) * NS + (tid & 3) * 4);
        }
        __builtin_amdgcn_sched_barrier(0);
        __builtin_amdgcn_s_setprio(1);
#pragma unroll
        for (int s8 = 0; s8 < 8; ++s8) {
            int col = ch * 128 + s8 * 16;
            half8_t bc;
            if (s8 == 0) bc = bfrA0; else if (s8 == 1) bc = bfrA1;
            else if (s8 == 2) bc = bfrA2; else if (s8 == 3) bc = bfrA3;
            else if (s8 == 4) bc = bfrB0; else if (s8 == 5) bc = bfrB1;
            else if (s8 == 6) bc = bfrB2; else bc = bfrB3;
            half8_t a0 = *(const half8_t*)&Abase[col];
            half8_t a1 = *(const half8_t*)&Abase[32 * AS + col];
            acc0 = __builtin_amdgcn_mfma_f32_32x32x16_f16(a0, bc, acc0, 0, 0, 0);
            acc1 = __builtin_amdgcn_mfma_f32_32x32x16_f16(a1, bc, acc1, 0, 0, 0);
        }
        __builtin_amdgcn_s_setprio(0);
        if (ch < 3) {
            *(half4_t*)&A[(r0) * AS + (ch + 1) * 128 + 4 * c4] = cvt4(s0);
            *(half4_t*)&A[(r0 + 16) * AS + (ch + 1) * 128 + 4 * c4] = cvt4(s1);
            *(half4_t*)&A[(r0 + 32) * AS + (ch + 1) * 128 + 4 * c4] = cvt4(s2);
            *(half4_t*)&A[(r0 + 48) * AS + (ch + 1) * 128 + 4 * c4] = cvt4(s3);
            s0 = n0; s1 = n1; s2 = n2; s3 = n3;
        } else {
            if (tid < 256)
                *(half4_t*)&A[(tid >> 2) * AS + 512 + (tid & 3) * 4] = cvt4(sst);
        }
        __builtin_amdgcn_sched_barrier(0);
        // next chunk's first-half B (or the t=32 tail B): issue BEFORE the
        // barrier so L2 latency drains while waves wait (vmcnt not drained).
        if (ch < 3) {
            bfrA0 = *(const half8_t*)(Wb + (size_t)((ch + 1) * 8 + 0) * 8192);
            bfrA1 = *(const half8_t*)(Wb + (size_t)((ch + 1) * 8 + 1) * 8192);
            bfrA2 = *(const half8_t*)(Wb + (size_t)((ch + 1) * 8 + 2) * 8192);
            bfrA3 = *(const half8_t*)(Wb + (size_t)((ch + 1) * 8 + 3) * 8192);
        } else {
            bfa = *(const half8_t*)(Wb + (size_t)32 * 8192);
        }
        asm volatile("s_waitcnt lgkmcnt(0)" ::: "memory");
        __builtin_amdgcn_sched_barrier(0);
        __builtin_amdgcn_s_barrier();
        __builtin_amdgcn_sched_barrier(0);
    }
    // final K-step of pass 1 (stats cols 512..527, t = 32)
    {
        half8_t a0 = *(const half8_t*)&Abase[512];
        half8_t a1 = *(const half8_t*)&Abase[32 * AS + 512];
        __builtin_amdgcn_s_setprio(1);
        acc0 = __builtin_amdgcn_mfma_f32_32x32x16_f16(a0, bfa, acc0, 0, 0, 0);
        acc1 = __builtin_amdgcn_mfma_f32_32x32x16_f16(a1, bfa, acc1, 0, 0, 0);
        __builtin_amdgcn_s_setprio(0);
    }

    // ---- prime pass-2 first THREE B pairs (latency hides under epilogue-1;
    //      staging regs s0..s3 are dead here, so +8 regs vs v7 is free) ----
    const half_t* Wb2 = Wb + 4096;  // cols +256
    half8_t pA0 = *(const half8_t*)(Wb2);
    half8_t pB0 = *(const half8_t*)(Wb2 + 8192);
    half8_t pA1 = *(const half8_t*)(Wb2 + 2 * 8192);
    half8_t pB1 = *(const half8_t*)(Wb2 + 3 * 8192);
    half8_t pA2 = *(const half8_t*)(Wb2 + 4 * 8192);
    half8_t pB2 = *(const half8_t*)(Wb2 + 5 * 8192);
    __builtin_amdgcn_sched_barrier(0);

    // ---- epilogue pass 1 ----
    {
        float g0[16], g1[16];
#pragma unroll
        for (int r = 0; r < 16; ++r) {
            g0[r] = gelu_erf(acc0[r] + qv1) * w21;
            g1[r] = gelu_erf(acc1[r] + qv1) * w21;
        }
        float rA = colreduce16(g0, ln);
        float rB = colreduce16(g1, ln);
        if (ln < 16) {
            int row = (ln & 3) + 8 * (ln >> 2) + 4 * hi;
            Llds[row][w] = rA;
            Llds[32 + row][w] = rB;
        }
    }

    // ---- pass 2: cols 256..511 over k 0..527, 3-deep register-buffered B ----
    acc0 = (floatx16){0,0,0,0,0,0,0,0,0,0,0,0,0,0,0,0};
    acc1 = (floatx16){0,0,0,0,0,0,0,0,0,0,0,0,0,0,0,0};
#pragma unroll 1
    for (int t2 = 0; t2 < 16; ++t2) {
        int tn = 2 * t2 + 6;
        if (tn > 32) tn = 32;
        int tn1 = tn + 1;
        if (tn1 > 32) tn1 = 32;   // never touch t=33 (doesn't exist)
        half8_t nA = *(const half8_t*)(Wb2 + (size_t)tn * 8192);
        half8_t nB = *(const half8_t*)(Wb2 + (size_t)tn1 * 8192);
        int col = t2 * 32;
        half8_t a0 = *(const half8_t*)&Abase[col];
        half8_t a1 = *(const half8_t*)&Abase[32 * AS + col];
        __builtin_amdgcn_s_setprio(1);
        acc0 = __builtin_amdgcn_mfma_f32_32x32x16_f16(a0, pA0, acc0, 0, 0, 0);
        acc1 = __builtin_amdgcn_mfma_f32_32x32x16_f16(a1, pA0, acc1, 0, 0, 0);
        half8_t a0b = *(const half8_t*)&Abase[col + 16];
        half8_t a1b = *(const half8_t*)&Abase[32 * AS + col + 16];
        acc0 = __builtin_amdgcn_mfma_f32_32x32x16_f16(a0b, pB0, acc0, 0, 0, 0);
        acc1 = __builtin_amdgcn_mfma_f32_32x32x16_f16(a1b, pB0, acc1, 0, 0, 0);
        __builtin_amdgcn_s_setprio(0);
        pA0 = pA1; pB0 = pB1; pA1 = pA2; pB1 = pB2; pA2 = nA; pB2 = nB;
    }
    // pass-2 K-tail: stats cols 512..527 (t = 32, now in pA0: primed t=0..5,
    // 16 shifts consume t=0..31 pairs; pA0 ends holding the t=32 load)
    {
        half8_t a0 = *(const half8_t*)&Abase[512];
        half8_t a1 = *(const half8_t*)&Abase[32 * AS + 512];
        __builtin_amdgcn_s_setprio(1);
        acc0 = __builtin_amdgcn_mfma_f32_32x32x16_f16(a0, pA0, acc0, 0, 0, 0);
        acc1 = __builtin_amdgcn_mfma_f32_32x32x16_f16(a1, pA0, acc1, 0, 0, 0);
        __builtin_amdgcn_s_setprio(0);
    }

    // ---- epilogue pass 2 ----
    {
        float g0[16], g1[16];
#pragma unroll
        for (int r = 0; r < 16; ++r) {
            g0[r] = gelu_erf(acc0[r] + qv2) * w22;
            g1[r] = gelu_erf(acc1[r] + qv2) * w22;
        }
        float rA = colreduce16(g0, ln);
        float rB = colreduce16(g1, ln);
        if (ln < 16) {
            int row = (ln & 3) + 8 * (ln >> 2) + 4 * hi;
            Llds[row][8 + w] = rA;
            Llds[32 + row][8 + w] = rB;
        }
    }
    __syncthreads();   // Llds is cross-wave: barrier required

    // ---- softmax over K=64: ALL waves redundantly; lane l owns k=l ----
    {
        int k = l;
        float lsum = 0.0f;
#pragma unroll
        for (int j = 0; j < 16; ++j) lsum += Llds[k][j];
        float sim = Llds[k][16];   // prefetched at prologue
        float logit = lsum + sb2[0] + alpha[0] * sim;
        float mx = logit;
#pragma unroll
        for (int m = 1; m < 64; m <<= 1) mx = fmaxf(mx, __shfl_xor(mx, m, 64));
        float e = __expf(logit - mx);
        float s = e;
#pragma unroll
        for (int m = 1; m < 64; m <<= 1) s += __shfl_xor(s, m, 64);
        float at = e / s;
        attn_s[w][k] = at;                 // own wave's copy: DS in-order
        if (w == 0) attn_out[(size_t)b * NK + k] = at;
    }
    // NO barrier: each wave reads only its own attn_s[w] copy below.

    // ---- mix from LDS (half2 per thread): mixed[e'] = sum_k attn[k]*A[k][e'] ----
    if (tid < 264) {
        int c0 = 2 * tid;  // cols [c0, c0+1], covers 0..527 (real data only)
        float m0 = 0.0f, m1 = 0.0f;
#pragma unroll 8
        for (int k = 0; k < NK; ++k) {
            half2_t v = *(const half2_t*)&A[k * AS + c0];
            float aw = attn_s[w][k];
            m0 += aw * (float)v[0];
            m1 += aw * (float)v[1];
        }
        *(half2_t*)&mixed[(size_t)b * AS + c0] = (half2_t){(half_t)m0, (half_t)m1};
    } else if (tid < 270) {
        int z = tid - 264;  // zero cols 528..551 (6 x half4)
        half4_t hz = {};
        *(half4_t*)&mixed[(size_t)b * AS + 528 + 4 * z] = hz;
    }
}

// ---------------------------------------------------------------------------
// proj_kernel: out = gelu(mixed@pw1 + pb1) @ pw2 + pb2, both layers fused.
// 1024 threads = 16 waves (wave owns 32 cols) for better latency hiding.
__global__ __launch_bounds__(1024) void proj_kernel(
    const half_t* __restrict__ mixedp, const half_t* __restrict__ Wp1,
    const half_t* __restrict__ Wp2, const float* __restrict__ pb1,
    const float* __restrict__ pb2, float* __restrict__ out) {
    constexpr int AS3 = AS;
    __shared__ __align__(16) half_t A1[16 * AS3];
    int b0 = blockIdx.x * 16;
    int tid = threadIdx.x;
    const uint4* src = (const uint4*)(mixedp + (size_t)b0 * AS3);
    for (int i = tid; i < 1104; i += 1024) ((uint4*)A1)[i] = src[i];
    __syncthreads();

    int w = tid >> 6, l = tid & 63, lg = l >> 4, ln = l & 15;
    floatx4 acc[2] = { {0,0,0,0}, {0,0,0,0} };
    for (int t = 0; t < 17; ++t) {
        half8_t a = *(const half8_t*)&A1[ln * AS3 + t * 32 + 8 * lg];
#pragma unroll
        for (int ni = 0; ni < 2; ++ni) {
            int n = w * 32 + ni * 16 + ln;
            half8_t bf = *(const half8_t*)(Wp1 + ((size_t)t * NE + n) * 32 + 8 * lg);
            acc[ni] = __builtin_amdgcn_mfma_f32_16x16x32_f16(a, bf, acc[ni], 0, 0, 0);
        }
    }
    __syncthreads();
#pragma unroll
    for (int ni = 0; ni < 2; ++ni) {
        int col = w * 32 + ni * 16 + ln;
        float bias = pb1[col];
#pragma unroll
        for (int r = 0; r < 4; ++r) {
            int row = 4 * lg + r;
            A1[row * AS3 + col] = (half_t)gelu_erf(acc[ni][r] + bias);
        }
    }
    __syncthreads();
    floatx4 acc2[2] = { {0,0,0,0}, {0,0,0,0} };
    for (int t = 0; t < 16; ++t) {
        half8_t a = *(const half8_t*)&A1[ln * AS3 + t * 32 + 8 * lg];
#pragma unroll
        for (int ni = 0; ni < 2; ++ni) {
            int n = w * 32 + ni * 16 + ln;
            half8_t bf = *(const half8_t*)(Wp2 + ((size_t)t * NE + n) * 32 + 8 * lg);
            acc2[ni] = __builtin_amdgcn_mfma_f32_16x16x32_f16(a, bf, acc2[ni], 0, 0, 0);
        }
    }
#pragma unroll
    for (int ni = 0; ni < 2; ++ni) {
        int col = w * 32 + ni * 16 + ln;
        float bias = pb2[col];
#pragma unroll
        for (int r = 0; r < 4; ++r)
            out[(size_t)(b0 + 4 * lg + r) * NE + col] = acc2[ni][r] + bias;
    }
}

// ---------------------------------------------------------------------------
extern "C" void kernel_launch(void* const* d_in, const int* in_sizes, int n_in,
                              void* d_out, int out_size, void* d_ws, size_t ws_size,
                              hipStream_t stream) {
    (void)in_sizes; (void)n_in; (void)out_size; (void)ws_size;
    const float* q     = (const float*)d_in[0];
    const float* c     = (const float*)d_in[1];
    const float* nb    = (const float*)d_in[2];
    const float* st    = (const float*)d_in[3];
    const float* sw1   = (const float*)d_in[4];
    const float* sb1   = (const float*)d_in[5];
    const float* sw2   = (const float*)d_in[6];
    const float* sb2   = (const float*)d_in[7];
    const float* alpha = (const float*)d_in[8];
    const float* pw1   = (const float*)d_in[9];
    const float* pb1   = (const float*)d_in[10];
    const float* pw2   = (const float*)d_in[11];
    const float* pb2   = (const float*)d_in[12];

    char* ws = (char*)d_ws;
    half_t* Wq  = (half_t*)(ws + 0);          // 1024*512*2 = 1048576
    half_t* Wns = (half_t*)(ws + 1048576);    // 33*512*16*2 = 540672
    half_t* Wp1 = (half_t*)(ws + 1605632);    // 544*512*2  = 557056
    half_t* Wp2 = (half_t*)(ws + 2162688);    // 512*512*2  = 524288
    float*  qcb = (float*)(ws + 2686976);     // 2048*512*4 = 4194304
    half_t* mix = (half_t*)(ws + 6881280);    // 2048*552*2 = 2260992

    float* outp  = (float*)d_out;
    float* attnp = outp + (size_t)NBATCH * NE;

    pack_all<<<784, 256, 0, stream>>>(sw1, pw1, pw2, Wq, Wns, Wp1, Wp2);
    qc_kernel<<<256, 512, 0, stream>>>(q, c, Wq, sb1, qcb);
    main_kernel<<<2048, 512, 0, stream>>>(nb, st, Wns, qcb, sw2, sb2, alpha, attnp, mix);
    proj_kernel<<<128, 1024, 0, stream>>>(mix, Wp1, Wp2, pb1, pb2, outp);
}

// Round 9
// 170.276 us; speedup vs baseline: 1.2125x; 1.0428x over previous
//
#include <hip/hip_runtime.h>

typedef _Float16 half_t;
typedef _Float16 half2_t __attribute__((ext_vector_type(2)));
typedef _Float16 half4_t __attribute__((ext_vector_type(4)));
typedef _Float16 half8_t __attribute__((ext_vector_type(8)));
typedef float floatx4 __attribute__((ext_vector_type(4)));
typedef float floatx16 __attribute__((ext_vector_type(16)));

#define NE 512
#define NS 16
#define NBATCH 2048
#define NK 64
#define AS 552  // LDS row stride (halves)

// gelu(x) = 0.5 x (1 + erf(x/sqrt2)); erf via A&S 7.1.26 (|err|<=1.5e-7), branch-free.
__device__ __forceinline__ float gelu_erf(float x) {
    float z = x * 0.70710678118654752440f;
    float az2 = z * z;
    float az = __builtin_fabsf(z);
    float t = __builtin_amdgcn_rcpf(__builtin_fmaf(0.3275911f, az, 1.0f));
    float p = __builtin_fmaf(1.061405429f, t, -1.453152027f);
    p = __builtin_fmaf(p, t, 1.421413741f);
    p = __builtin_fmaf(p, t, -0.284496736f);
    p = __builtin_fmaf(p, t, 0.254829592f);
    p = p * t;
    float e = __expf(-az2);
    float erfa = __builtin_fmaf(-p, e, 1.0f);
    unsigned int u = __float_as_uint(erfa) ^ (__float_as_uint(z) & 0x80000000u);
    return 0.5f * x * (1.0f + __uint_as_float(u));
}

__device__ __forceinline__ half4_t cvt4(float4 v) {
    return (half4_t){(half_t)v.x, (half_t)v.y, (half_t)v.z, (half_t)v.w};
}

// packed 32-lane column reduction of 16 values: returns full col-sum of
// x[ln&15] at each lane (reduction over the 32-lane half).
__device__ __forceinline__ float colreduce16(const float (&x)[16], int lnb) {
    float y[8];
#pragma unroll
    for (int i = 0; i < 8; ++i) {
        float keep = (lnb & 1) ? x[2 * i + 1] : x[2 * i];
        float send = (lnb & 1) ? x[2 * i] : x[2 * i + 1];
        y[i] = keep + __shfl_xor(send, 1, 64);
    }
    float z[4];
#pragma unroll
    for (int i = 0; i < 4; ++i) {
        float keep = (lnb & 2) ? y[2 * i + 1] : y[2 * i];
        float send = (lnb & 2) ? y[2 * i] : y[2 * i + 1];
        z[i] = keep + __shfl_xor(send, 2, 64);
    }
    float u[2];
#pragma unroll
    for (int i = 0; i < 2; ++i) {
        float keep = (lnb & 4) ? z[2 * i + 1] : z[2 * i];
        float send = (lnb & 4) ? z[2 * i] : z[2 * i + 1];
        u[i] = keep + __shfl_xor(send, 4, 64);
    }
    float keep = (lnb & 8) ? u[1] : u[0];
    float send = (lnb & 8) ? u[0] : u[1];
    float v = keep + __shfl_xor(send, 8, 64);
    v += __shfl_xor(v, 16, 64);
    return v;
}

// ---------------------------------------------------------------------------
// pack bodies (device): 16x16x32 layout dst[(t*512+n)*32+kk] and 32x32x16
// layout dst[(t*512+n)*16+kk]. Shared tile passed in (max 32*68 halves).
__device__ void pack_w_body(const float* __restrict__ src, half_t* __restrict__ dst,
                            int Ksrc, int t, int nb0, half_t* tile) {
    int tid = threadIdx.x;
#pragma unroll
    for (int i = 0; i < 8; ++i) {
        int idx = tid + i * 256;
        int kk = idx >> 6, np = idx & 63;
        int k = t * 32 + kk;
        float v = (k < Ksrc) ? src[(size_t)k * NE + nb0 + np] : 0.0f;
        tile[kk * 68 + np] = (half_t)v;
    }
    __syncthreads();
#pragma unroll
    for (int i = 0; i < 8; ++i) {
        int idx = tid + i * 256;
        int np = idx >> 5, kk = idx & 31;
        dst[((size_t)t * NE + nb0 + np) * 32 + kk] = tile[kk * 68 + np];
    }
}

__device__ void pack_w32_body(const float* __restrict__ src, half_t* __restrict__ dst,
                              int Ksrc, int t, int nb0, half_t* tile) {
    int tid = threadIdx.x;
#pragma unroll
    for (int i = 0; i < 4; ++i) {
        int idx = tid + i * 256;
        int kk = idx >> 6, n = idx & 63;
        int k = t * 16 + kk;
        float v = (k < Ksrc) ? src[(size_t)k * NE + nb0 + n] : 0.0f;
        tile[kk * 68 + n] = (half_t)v;
    }
    __syncthreads();
    int n = threadIdx.x >> 2, q = threadIdx.x & 3;
    half4_t h = {tile[(q * 4) * 68 + n], tile[(q * 4 + 1) * 68 + n],
                 tile[(q * 4 + 2) * 68 + n], tile[(q * 4 + 3) * 68 + n]};
    *(half4_t*)&dst[((size_t)t * NE + nb0 + n) * 16 + q * 4] = h;
}

// pack_all: one launch does all four weight packs. Block ranges:
// [0,256) Wq | [256,520) Wns (32x32 layout) | [520,656) Wp1 | [656,784) Wp2.
__global__ __launch_bounds__(256) void pack_all(
    const float* __restrict__ sw1, const float* __restrict__ pw1,
    const float* __restrict__ pw2, half_t* __restrict__ Wq,
    half_t* __restrict__ Wns, half_t* __restrict__ Wp1, half_t* __restrict__ Wp2) {
    __shared__ half_t tile[32 * 68];
    int bx = blockIdx.x;
    if (bx < 256) {
        pack_w_body(sw1, Wq, 1024, bx >> 3, (bx & 7) * 64, tile);
    } else if (bx < 520) {
        int b2 = bx - 256;
        pack_w32_body(sw1 + (size_t)1024 * NE, Wns, 528, b2 >> 3, (b2 & 7) * 64, tile);
    } else if (bx < 656) {
        int b3 = bx - 520;
        pack_w_body(pw1, Wp1, 528, b3 >> 3, (b3 & 7) * 64, tile);
    } else {
        int b4 = bx - 656;
        pack_w_body(pw2, Wp2, 512, b4 >> 3, (b4 & 7) * 64, tile);
    }
}

// ---------------------------------------------------------------------------
// qc_kernel: qc[b,n] = q[b]@sw1[0:512] + c[b]@sw1[512:1024] + sb1[n].
// grid = 256: bx>>1 = 16-row group, bx&1 = 256-col half (all CUs busy).
__global__ __launch_bounds__(512) void qc_kernel(const float* __restrict__ q,
                                                 const float* __restrict__ c,
                                                 const half_t* __restrict__ Wq,
                                                 const float* __restrict__ sb1,
                                                 float* __restrict__ qcb) {
    constexpr int AS1 = 1032;
    __shared__ __align__(16) half_t A1[16 * AS1];
    int b0 = (blockIdx.x >> 1) * 16;
    int nh = (blockIdx.x & 1) * 256;
    int tid = threadIdx.x;
#pragma unroll
    for (int i = 0; i < 8; ++i) {
        int f = tid + i * 512;
        int row = f >> 8;
        int c4 = f & 255;
        const float* srcp = (c4 < 128) ? (q + (size_t)(b0 + row) * NE + c4 * 4)
                                       : (c + (size_t)(b0 + row) * NE + (c4 - 128) * 4);
        float4 v = *(const float4*)srcp;
        *(half4_t*)&A1[row * AS1 + c4 * 4] = cvt4(v);
    }
    __syncthreads();
    int w = tid >> 6, l = tid & 63, lg = l >> 4, ln = l & 15;
    floatx4 acc[2] = { {0,0,0,0}, {0,0,0,0} };
    for (int t = 0; t < 32; ++t) {
        half8_t a = *(const half8_t*)&A1[ln * AS1 + t * 32 + 8 * lg];
#pragma unroll
        for (int ni = 0; ni < 2; ++ni) {
            int n = nh + w * 32 + ni * 16 + ln;
            half8_t bf = *(const half8_t*)(Wq + ((size_t)t * NE + n) * 32 + 8 * lg);
            acc[ni] = __builtin_amdgcn_mfma_f32_16x16x32_f16(a, bf, acc[ni], 0, 0, 0);
        }
    }
#pragma unroll
    for (int ni = 0; ni < 2; ++ni) {
        int col = nh + w * 32 + ni * 16 + ln;
        float bias = sb1[col];
#pragma unroll
        for (int r = 0; r < 4; ++r) {
            int row = 4 * lg + r;
            qcb[(size_t)(b0 + row) * NE + col] = acc[ni][r] + bias;
        }
    }
}

// ---------------------------------------------------------------------------
// main_kernel v10 = v7 EXACTLY in the GEMM region (165.4us, the converged
// vertex: full-resident A, 2 blocks/CU, 2-pass acc-32, setprio, sim-prefetch;
// v7 sits FLUSH at the 4-waves/SIMD register cap -- v4 (+32 regs) and v9
// (+16 regs) both spilled, so NO added live state anywhere near the K-loops)
// + one tail-only change: mix spread over ALL 512 threads (1 col each, was
// 264 threads x 2 cols) -- halves the longest-thread tail work, engages
// waves 5-7, keeps per-wave attn_s (no barrier), 2-way-free LDS banks.
__global__ __launch_bounds__(512, 4) void main_kernel(
    const float* __restrict__ neighbors, const float* __restrict__ stats,
    const half_t* __restrict__ Wns, const float* __restrict__ qcb,
    const float* __restrict__ sw2, const float* __restrict__ sb2,
    const float* __restrict__ alpha, float* __restrict__ attn_out,
    half_t* __restrict__ mixed) {
    __shared__ __align__(16) half_t A[64 * AS];  // 70656 B
    __shared__ float Llds[64][17];
    __shared__ float attn_s[8][64];              // per-wave copy: no tail barrier

    int b = blockIdx.x;
    int tid = threadIdx.x;
    const float* nb = neighbors + (size_t)b * NK * NE;
    const float* st = stats + (size_t)b * NK * NS;

    int r0 = tid >> 5;     // 0..15 (staging rows r0+16i)
    int c4 = tid & 31;     // float4-col within 128-col chunk
    int w = tid >> 6;      // wave 0..7
    int l = tid & 63, ln = l & 31, hi = l >> 5;
    const half_t* Abase = A + ln * AS + 8 * hi;
    const half_t* Wb = Wns + ((size_t)(w * 32 + ln)) * 16 + 8 * hi;  // + t*8192

    // ---- prologue: stage chunk 0; issue chunk 1; preload epilogue scalars;
    //      prefetch softmax sim column into the Llds pad col ----
    float4 s0, s1, s2, s3, sst;
    float qv1, w21, qv2, w22;
    {
        float4 p0 = *(const float4*)(nb + (size_t)(r0) * NE + 4 * c4);
        float4 p1 = *(const float4*)(nb + (size_t)(r0 + 16) * NE + 4 * c4);
        float4 p2 = *(const float4*)(nb + (size_t)(r0 + 32) * NE + 4 * c4);
        float4 p3 = *(const float4*)(nb + (size_t)(r0 + 48) * NE + 4 * c4);
        __builtin_amdgcn_sched_barrier(0);
        s0 = *(const float4*)(nb + (size_t)(r0) * NE + 128 + 4 * c4);
        s1 = *(const float4*)(nb + (size_t)(r0 + 16) * NE + 128 + 4 * c4);
        s2 = *(const float4*)(nb + (size_t)(r0 + 32) * NE + 128 + 4 * c4);
        s3 = *(const float4*)(nb + (size_t)(r0 + 48) * NE + 128 + 4 * c4);
        qv1 = qcb[(size_t)b * NE + w * 32 + ln];
        w21 = sw2[w * 32 + ln];
        qv2 = qcb[(size_t)b * NE + 256 + w * 32 + ln];
        w22 = sw2[256 + w * 32 + ln];
        __builtin_amdgcn_sched_barrier(0);
        *(half4_t*)&A[(r0) * AS + 4 * c4] = cvt4(p0);
        *(half4_t*)&A[(r0 + 16) * AS + 4 * c4] = cvt4(p1);
        *(half4_t*)&A[(r0 + 32) * AS + 4 * c4] = cvt4(p2);
        *(half4_t*)&A[(r0 + 48) * AS + 4 * c4] = cvt4(p3);
        // softmax sim column -> unused Llds pad col (read after final barrier)
        if (tid < 64) Llds[tid][16] = st[tid * NS + (NS - 1)];
    }
    asm volatile("s_waitcnt lgkmcnt(0)" ::: "memory");
    __builtin_amdgcn_sched_barrier(0);
    __builtin_amdgcn_s_barrier();
    __builtin_amdgcn_sched_barrier(0);

    floatx16 acc0 = {0,0,0,0,0,0,0,0,0,0,0,0,0,0,0,0};
    floatx16 acc1 = {0,0,0,0,0,0,0,0,0,0,0,0,0,0,0,0};

    // ---- pass 1, pipelined chunks 0..3 (8 K-steps of 16 each) ----
#pragma unroll 1
    for (int ch = 0; ch < 4; ++ch) {
        half8_t bfr[8];
#pragma unroll
        for (int s8 = 0; s8 < 8; ++s8)
            bfr[s8] = *(const half8_t*)(Wb + (size_t)(ch * 8 + s8) * 8192);
        __builtin_amdgcn_sched_barrier(0);
        float4 n0, n1, n2, n3;
        if (ch < 2) {
            n0 = *(const float4*)(nb + (size_t)(r0) * NE + (ch + 2) * 128 + 4 * c4);
            n1 = *(const float4*)(nb + (size_t)(r0 + 16) * NE + (ch + 2) * 128 + 4 * c4);
            n2 = *(const float4*)(nb + (size_t)(r0 + 32) * NE + (ch + 2) * 128 + 4 * c4);
            n3 = *(const float4*)(nb + (size_t)(r0 + 48) * NE + (ch + 2) * 128 + 4 * c4);
        } else if (ch == 2) {
            if (tid < 256)
                sst = *(const float4*)(st + (tid >> 2) * NS + (tid & 3) * 4);
        }
        __builtin_amdgcn_sched_barrier(0);
        __builtin_amdgcn_s_setprio(1);
#pragma unroll
        for (int s8 = 0; s8 < 8; ++s8) {
            int col = ch * 128 + s8 * 16;
            half8_t a0 = *(const half8_t*)&Abase[col];
            half8_t a1 = *(const half8_t*)&Abase[32 * AS + col];
            acc0 = __builtin_amdgcn_mfma_f32_32x32x16_f16(a0, bfr[s8], acc0, 0, 0, 0);
            acc1 = __builtin_amdgcn_mfma_f32_32x32x16_f16(a1, bfr[s8], acc1, 0, 0, 0);
        }
        __builtin_amdgcn_s_setprio(0);
        if (ch < 3) {
            *(half4_t*)&A[(r0) * AS + (ch + 1) * 128 + 4 * c4] = cvt4(s0);
            *(half4_t*)&A[(r0 + 16) * AS + (ch + 1) * 128 + 4 * c4] = cvt4(s1);
            *(half4_t*)&A[(r0 + 32) * AS + (ch + 1) * 128 + 4 * c4] = cvt4(s2);
            *(half4_t*)&A[(r0 + 48) * AS + (ch + 1) * 128 + 4 * c4] = cvt4(s3);
            s0 = n0; s1 = n1; s2 = n2; s3 = n3;
        } else {
            if (tid < 256)
                *(half4_t*)&A[(tid >> 2) * AS + 512 + (tid & 3) * 4] = cvt4(sst);
        }
        asm volatile("s_waitcnt lgkmcnt(0)" ::: "memory");
        __builtin_amdgcn_sched_barrier(0);
        __builtin_amdgcn_s_barrier();
        __builtin_amdgcn_sched_barrier(0);
    }
    // final K-step of pass 1 (stats cols 512..527, t = 32)
    {
        half8_t bfa = *(const half8_t*)(Wb + (size_t)32 * 8192);
        half8_t a0 = *(const half8_t*)&Abase[512];
        half8_t a1 = *(const half8_t*)&Abase[32 * AS + 512];
        __builtin_amdgcn_s_setprio(1);
        acc0 = __builtin_amdgcn_mfma_f32_32x32x16_f16(a0, bfa, acc0, 0, 0, 0);
        acc1 = __builtin_amdgcn_mfma_f32_32x32x16_f16(a1, bfa, acc1, 0, 0, 0);
        __builtin_amdgcn_s_setprio(0);
    }

    // ---- prime pass-2 first two B pairs (latency hides under epilogue-1) ----
    const half_t* Wb2 = Wb + 4096;  // cols +256
    half8_t pA0 = *(const half8_t*)(Wb2);
    half8_t pB0 = *(const half8_t*)(Wb2 + 8192);
    half8_t pA1 = *(const half8_t*)(Wb2 + 2 * 8192);
    half8_t pB1 = *(const half8_t*)(Wb2 + 3 * 8192);
    __builtin_amdgcn_sched_barrier(0);

    // ---- epilogue pass 1 ----
    {
        float g0[16], g1[16];
#pragma unroll
        for (int r = 0; r < 16; ++r) {
            g0[r] = gelu_erf(acc0[r] + qv1) * w21;
            g1[r] = gelu_erf(acc1[r] + qv1) * w21;
        }
        float rA = colreduce16(g0, ln);
        float rB = colreduce16(g1, ln);
        if (ln < 16) {
            int row = (ln & 3) + 8 * (ln >> 2) + 4 * hi;
            Llds[row][w] = rA;
            Llds[32 + row][w] = rB;
        }
    }

    // ---- pass 2: cols 256..511 over k 0..527, 2-deep double-buffered B ----
    acc0 = (floatx16){0,0,0,0,0,0,0,0,0,0,0,0,0,0,0,0};
    acc1 = (floatx16){0,0,0,0,0,0,0,0,0,0,0,0,0,0,0,0};
#pragma unroll 1
    for (int t2 = 0; t2 < 16; ++t2) {
        int tn = 2 * t2 + 4;
        if (tn > 32) tn = 32;
        int tn1 = tn + 1;
        if (tn1 > 32) tn1 = 32;   // never touch t=33 (doesn't exist)
        half8_t nA = *(const half8_t*)(Wb2 + (size_t)tn * 8192);
        half8_t nB = *(const half8_t*)(Wb2 + (size_t)tn1 * 8192);
        int col = t2 * 32;
        half8_t a0 = *(const half8_t*)&Abase[col];
        half8_t a1 = *(const half8_t*)&Abase[32 * AS + col];
        __builtin_amdgcn_s_setprio(1);
        acc0 = __builtin_amdgcn_mfma_f32_32x32x16_f16(a0, pA0, acc0, 0, 0, 0);
        acc1 = __builtin_amdgcn_mfma_f32_32x32x16_f16(a1, pA0, acc1, 0, 0, 0);
        half8_t a0b = *(const half8_t*)&Abase[col + 16];
        half8_t a1b = *(const half8_t*)&Abase[32 * AS + col + 16];
        acc0 = __builtin_amdgcn_mfma_f32_32x32x16_f16(a0b, pB0, acc0, 0, 0, 0);
        acc1 = __builtin_amdgcn_mfma_f32_32x32x16_f16(a1b, pB0, acc1, 0, 0, 0);
        __builtin_amdgcn_s_setprio(0);
        pA0 = pA1; pB0 = pB1; pA1 = nA; pB1 = nB;
    }
    // pass-2 K-tail: stats cols 512..527 (t = 32, now in pA0)
    {
        half8_t a0 = *(const half8_t*)&Abase[512];
        half8_t a1 = *(const half8_t*)&Abase[32 * AS + 512];
        __builtin_amdgcn_s_setprio(1);
        acc0 = __builtin_amdgcn_mfma_f32_32x32x16_f16(a0, pA0, acc0, 0, 0, 0);
        acc1 = __builtin_amdgcn_mfma_f32_32x32x16_f16(a1, pA0, acc1, 0, 0, 0);
        __builtin_amdgcn_s_setprio(0);
    }

    // ---- epilogue pass 2 ----
    {
        float g0[16], g1[16];
#pragma unroll
        for (int r = 0; r < 16; ++r) {
            g0[r] = gelu_erf(acc0[r] + qv2) * w22;
            g1[r] = gelu_erf(acc1[r] + qv2) * w22;
        }
        float rA = colreduce16(g0, ln);
        float rB = colreduce16(g1, ln);
        if (ln < 16) {
            int row = (ln & 3) + 8 * (ln >> 2) + 4 * hi;
            Llds[row][8 + w] = rA;
            Llds[32 + row][8 + w] = rB;
        }
    }
    __syncthreads();   // Llds is cross-wave: barrier required

    // ---- softmax over K=64: ALL waves redundantly; lane l owns k=l ----
    {
        int k = l;
        float lsum = 0.0f;
#pragma unroll
        for (int j = 0; j < 16; ++j) lsum += Llds[k][j];
        float sim = Llds[k][16];   // prefetched at prologue
        float logit = lsum + sb2[0] + alpha[0] * sim;
        float mx = logit;
#pragma unroll
        for (int m = 1; m < 64; m <<= 1) mx = fmaxf(mx, __shfl_xor(mx, m, 64));
        float e = __expf(logit - mx);
        float s = e;
#pragma unroll
        for (int m = 1; m < 64; m <<= 1) s += __shfl_xor(s, m, 64);
        float at = e / s;
        attn_s[w][k] = at;                 // own wave's copy: DS in-order
        if (w == 0) attn_out[(size_t)b * NK + k] = at;
    }
    // NO barrier: each wave reads only its own attn_s[w] copy below.

    // ---- mix from LDS, ALL 512 threads (1 col each; was 264 x 2 cols):
    //      mixed[e'] = sum_k attn[k]*A[k][e'] ----
    {
        int c0 = tid;  // col 0..511
        float m0 = 0.0f;
#pragma unroll 8
        for (int k = 0; k < NK; ++k) {
            float aw = attn_s[w][k];
            m0 += aw * (float)A[k * AS + c0];
        }
        mixed[(size_t)b * AS + c0] = (half_t)m0;
        if (tid < 16) {  // stats cols 512..527 (wave 0)
            int cs = 512 + tid;
            float n0 = 0.0f;
#pragma unroll 8
            for (int k = 0; k < NK; ++k)
                n0 += attn_s[w][k] * (float)A[k * AS + cs];
            mixed[(size_t)b * AS + cs] = (half_t)n0;
        } else if (tid < 28) {
            int z = tid - 16;  // zero cols 528..551 (12 x half2)
            *(half2_t*)&mixed[(size_t)b * AS + 528 + 2 * z] = (half2_t){};
        }
    }
}

// ---------------------------------------------------------------------------
// proj_kernel: out = gelu(mixed@pw1 + pb1) @ pw2 + pb2, both layers fused.
// 1024 threads = 16 waves (wave owns 32 cols) for better latency hiding.
__global__ __launch_bounds__(1024) void proj_kernel(
    const half_t* __restrict__ mixedp, const half_t* __restrict__ Wp1,
    const half_t* __restrict__ Wp2, const float* __restrict__ pb1,
    const float* __restrict__ pb2, float* __restrict__ out) {
    constexpr int AS3 = AS;
    __shared__ __align__(16) half_t A1[16 * AS3];
    int b0 = blockIdx.x * 16;
    int tid = threadIdx.x;
    const uint4* src = (const uint4*)(mixedp + (size_t)b0 * AS3);
    for (int i = tid; i < 1104; i += 1024) ((uint4*)A1)[i] = src[i];
    __syncthreads();

    int w = tid >> 6, l = tid & 63, lg = l >> 4, ln = l & 15;
    floatx4 acc[2] = { {0,0,0,0}, {0,0,0,0} };
    for (int t = 0; t < 17; ++t) {
        half8_t a = *(const half8_t*)&A1[ln * AS3 + t * 32 + 8 * lg];
#pragma unroll
        for (int ni = 0; ni < 2; ++ni) {
            int n = w * 32 + ni * 16 + ln;
            half8_t bf = *(const half8_t*)(Wp1 + ((size_t)t * NE + n) * 32 + 8 * lg);
            acc[ni] = __builtin_amdgcn_mfma_f32_16x16x32_f16(a, bf, acc[ni], 0, 0, 0);
        }
    }
    __syncthreads();
#pragma unroll
    for (int ni = 0; ni < 2; ++ni) {
        int col = w * 32 + ni * 16 + ln;
        float bias = pb1[col];
#pragma unroll
        for (int r = 0; r < 4; ++r) {
            int row = 4 * lg + r;
            A1[row * AS3 + col] = (half_t)gelu_erf(acc[ni][r] + bias);
        }
    }
    __syncthreads();
    floatx4 acc2[2] = { {0,0,0,0}, {0,0,0,0} };
    for (int t = 0; t < 16; ++t) {
        half8_t a = *(const half8_t*)&A1[ln * AS3 + t * 32 + 8 * lg];
#pragma unroll
        for (int ni = 0; ni < 2; ++ni) {
            int n = w * 32 + ni * 16 + ln;
            half8_t bf = *(const half8_t*)(Wp2 + ((size_t)t * NE + n) * 32 + 8 * lg);
            acc2[ni] = __builtin_amdgcn_mfma_f32_16x16x32_f16(a, bf, acc2[ni], 0, 0, 0);
        }
    }
#pragma unroll
    for (int ni = 0; ni < 2; ++ni) {
        int col = w * 32 + ni * 16 + ln;
        float bias = pb2[col];
#pragma unroll
        for (int r = 0; r < 4; ++r)
            out[(size_t)(b0 + 4 * lg + r) * NE + col] = acc2[ni][r] + bias;
    }
}

// ---------------------------------------------------------------------------
extern "C" void kernel_launch(void* const* d_in, const int* in_sizes, int n_in,
                              void* d_out, int out_size, void* d_ws, size_t ws_size,
                              hipStream_t stream) {
    (void)in_sizes; (void)n_in; (void)out_size; (void)ws_size;
    const float* q     = (const float*)d_in[0];
    const float* c     = (const float*)d_in[1];
    const float* nb    = (const float*)d_in[2];
    const float* st    = (const float*)d_in[3];
    const float* sw1   = (const float*)d_in[4];
    const float* sb1   = (const float*)d_in[5];
    const float* sw2   = (const float*)d_in[6];
    const float* sb2   = (const float*)d_in[7];
    const float* alpha = (const float*)d_in[8];
    const float* pw1   = (const float*)d_in[9];
    const float* pb1   = (const float*)d_in[10];
    const float* pw2   = (const float*)d_in[11];
    const float* pb2   = (const float*)d_in[12];

    char* ws = (char*)d_ws;
    half_t* Wq  = (half_t*)(ws + 0);          // 1024*512*2 = 1048576
    half_t* Wns = (half_t*)(ws + 1048576);    // 33*512*16*2 = 540672
    half_t* Wp1 = (half_t*)(ws + 1605632);    // 544*512*2  = 557056
    half_t* Wp2 = (half_t*)(ws + 2162688);    // 512*512*2  = 524288
    float*  qcb = (float*)(ws + 2686976);     // 2048*512*4 = 4194304
    half_t* mix = (half_t*)(ws + 6881280);    // 2048*552*2 = 2260992

    float* outp  = (float*)d_out;
    float* attnp = outp + (size_t)NBATCH * NE;

    pack_all<<<784, 256, 0, stream>>>(sw1, pw1, pw2, Wq, Wns, Wp1, Wp2);
    qc_kernel<<<256, 512, 0, stream>>>(q, c, Wq, sb1, qcb);
    main_kernel<<<2048, 512, 0, stream>>>(nb, st, Wns, qcb, sw2, sb2, alpha, attnp, mix);
    proj_kernel<<<128, 1024, 0, stream>>>(mix, Wp1, Wp2, pb1, pb2, outp);
}

// Round 10
// 170.246 us; speedup vs baseline: 1.2127x; 1.0002x over previous
//
#include <hip/hip_runtime.h>

typedef _Float16 half_t;
typedef _Float16 half2_t __attribute__((ext_vector_type(2)));
typedef _Float16 half4_t __attribute__((ext_vector_type(4)));
typedef _Float16 half8_t __attribute__((ext_vector_type(8)));
typedef float floatx4 __attribute__((ext_vector_type(4)));
typedef float floatx16 __attribute__((ext_vector_type(16)));

#define NE 512
#define NS 16
#define NBATCH 2048
#define NK 64
#define AS 552  // LDS row stride (halves)

// gelu(x) = 0.5 x (1 + erf(x/sqrt2)); erf via A&S 7.1.26 (|err|<=1.5e-7), branch-free.
__device__ __forceinline__ float gelu_erf(float x) {
    float z = x * 0.70710678118654752440f;
    float az2 = z * z;
    float az = __builtin_fabsf(z);
    float t = __builtin_amdgcn_rcpf(__builtin_fmaf(0.3275911f, az, 1.0f));
    float p = __builtin_fmaf(1.061405429f, t, -1.453152027f);
    p = __builtin_fmaf(p, t, 1.421413741f);
    p = __builtin_fmaf(p, t, -0.284496736f);
    p = __builtin_fmaf(p, t, 0.254829592f);
    p = p * t;
    float e = __expf(-az2);
    float erfa = __builtin_fmaf(-p, e, 1.0f);
    unsigned int u = __float_as_uint(erfa) ^ (__float_as_uint(z) & 0x80000000u);
    return 0.5f * x * (1.0f + __uint_as_float(u));
}

__device__ __forceinline__ half4_t cvt4(float4 v) {
    return (half4_t){(half_t)v.x, (half_t)v.y, (half_t)v.z, (half_t)v.w};
}

// packed 32-lane column reduction of 16 values: returns full col-sum of
// x[ln&15] at each lane (reduction over the 32-lane half).
__device__ __forceinline__ float colreduce16(const float (&x)[16], int lnb) {
    float y[8];
#pragma unroll
    for (int i = 0; i < 8; ++i) {
        float keep = (lnb & 1) ? x[2 * i + 1] : x[2 * i];
        float send = (lnb & 1) ? x[2 * i] : x[2 * i + 1];
        y[i] = keep + __shfl_xor(send, 1, 64);
    }
    float z[4];
#pragma unroll
    for (int i = 0; i < 4; ++i) {
        float keep = (lnb & 2) ? y[2 * i + 1] : y[2 * i];
        float send = (lnb & 2) ? y[2 * i] : y[2 * i + 1];
        z[i] = keep + __shfl_xor(send, 2, 64);
    }
    float u[2];
#pragma unroll
    for (int i = 0; i < 2; ++i) {
        float keep = (lnb & 4) ? z[2 * i + 1] : z[2 * i];
        float send = (lnb & 4) ? z[2 * i] : z[2 * i + 1];
        u[i] = keep + __shfl_xor(send, 4, 64);
    }
    float keep = (lnb & 8) ? u[1] : u[0];
    float send = (lnb & 8) ? u[0] : u[1];
    float v = keep + __shfl_xor(send, 8, 64);
    v += __shfl_xor(v, 16, 64);
    return v;
}

// ---------------------------------------------------------------------------
// pack bodies (device): 16x16x32 layout dst[(t*512+n)*32+kk] and 32x32x16
// layout dst[(t*512+n)*16+kk]. Shared tile passed in (max 32*68 halves).
__device__ void pack_w_body(const float* __restrict__ src, half_t* __restrict__ dst,
                            int Ksrc, int t, int nb0, half_t* tile) {
    int tid = threadIdx.x;
#pragma unroll
    for (int i = 0; i < 8; ++i) {
        int idx = tid + i * 256;
        int kk = idx >> 6, np = idx & 63;
        int k = t * 32 + kk;
        float v = (k < Ksrc) ? src[(size_t)k * NE + nb0 + np] : 0.0f;
        tile[kk * 68 + np] = (half_t)v;
    }
    __syncthreads();
#pragma unroll
    for (int i = 0; i < 8; ++i) {
        int idx = tid + i * 256;
        int np = idx >> 5, kk = idx & 31;
        dst[((size_t)t * NE + nb0 + np) * 32 + kk] = tile[kk * 68 + np];
    }
}

__device__ void pack_w32_body(const float* __restrict__ src, half_t* __restrict__ dst,
                              int Ksrc, int t, int nb0, half_t* tile) {
    int tid = threadIdx.x;
#pragma unroll
    for (int i = 0; i < 4; ++i) {
        int idx = tid + i * 256;
        int kk = idx >> 6, n = idx & 63;
        int k = t * 16 + kk;
        float v = (k < Ksrc) ? src[(size_t)k * NE + nb0 + n] : 0.0f;
        tile[kk * 68 + n] = (half_t)v;
    }
    __syncthreads();
    int n = threadIdx.x >> 2, q = threadIdx.x & 3;
    half4_t h = {tile[(q * 4) * 68 + n], tile[(q * 4 + 1) * 68 + n],
                 tile[(q * 4 + 2) * 68 + n], tile[(q * 4 + 3) * 68 + n]};
    *(half4_t*)&dst[((size_t)t * NE + nb0 + n) * 16 + q * 4] = h;
}

// pack_all: one launch does all four weight packs. Block ranges:
// [0,256) Wq | [256,520) Wns (32x32 layout) | [520,656) Wp1 | [656,784) Wp2.
__global__ __launch_bounds__(256) void pack_all(
    const float* __restrict__ sw1, const float* __restrict__ pw1,
    const float* __restrict__ pw2, half_t* __restrict__ Wq,
    half_t* __restrict__ Wns, half_t* __restrict__ Wp1, half_t* __restrict__ Wp2) {
    __shared__ half_t tile[32 * 68];
    int bx = blockIdx.x;
    if (bx < 256) {
        pack_w_body(sw1, Wq, 1024, bx >> 3, (bx & 7) * 64, tile);
    } else if (bx < 520) {
        int b2 = bx - 256;
        pack_w32_body(sw1 + (size_t)1024 * NE, Wns, 528, b2 >> 3, (b2 & 7) * 64, tile);
    } else if (bx < 656) {
        int b3 = bx - 520;
        pack_w_body(pw1, Wp1, 528, b3 >> 3, (b3 & 7) * 64, tile);
    } else {
        int b4 = bx - 656;
        pack_w_body(pw2, Wp2, 512, b4 >> 3, (b4 & 7) * 64, tile);
    }
}

// ---------------------------------------------------------------------------
// qc_kernel: qc[b,n] = q[b]@sw1[0:512] + c[b]@sw1[512:1024] + sb1[n].
// grid = 256: bx>>1 = 16-row group, bx&1 = 256-col half (all CUs busy).
__global__ __launch_bounds__(512) void qc_kernel(const float* __restrict__ q,
                                                 const float* __restrict__ c,
                                                 const half_t* __restrict__ Wq,
                                                 const float* __restrict__ sb1,
                                                 float* __restrict__ qcb) {
    constexpr int AS1 = 1032;
    __shared__ __align__(16) half_t A1[16 * AS1];
    int b0 = (blockIdx.x >> 1) * 16;
    int nh = (blockIdx.x & 1) * 256;
    int tid = threadIdx.x;
#pragma unroll
    for (int i = 0; i < 8; ++i) {
        int f = tid + i * 512;
        int row = f >> 8;
        int c4 = f & 255;
        const float* srcp = (c4 < 128) ? (q + (size_t)(b0 + row) * NE + c4 * 4)
                                       : (c + (size_t)(b0 + row) * NE + (c4 - 128) * 4);
        float4 v = *(const float4*)srcp;
        *(half4_t*)&A1[row * AS1 + c4 * 4] = cvt4(v);
    }
    __syncthreads();
    int w = tid >> 6, l = tid & 63, lg = l >> 4, ln = l & 15;
    floatx4 acc[2] = { {0,0,0,0}, {0,0,0,0} };
    for (int t = 0; t < 32; ++t) {
        half8_t a = *(const half8_t*)&A1[ln * AS1 + t * 32 + 8 * lg];
#pragma unroll
        for (int ni = 0; ni < 2; ++ni) {
            int n = nh + w * 32 + ni * 16 + ln;
            half8_t bf = *(const half8_t*)(Wq + ((size_t)t * NE + n) * 32 + 8 * lg);
            acc[ni] = __builtin_amdgcn_mfma_f32_16x16x32_f16(a, bf, acc[ni], 0, 0, 0);
        }
    }
#pragma unroll
    for (int ni = 0; ni < 2; ++ni) {
        int col = nh + w * 32 + ni * 16 + ln;
        float bias = sb1[col];
#pragma unroll
        for (int r = 0; r < 4; ++r) {
            int row = 4 * lg + r;
            qcb[(size_t)(b0 + row) * NE + col] = acc[ni][r] + bias;
        }
    }
}

// ---------------------------------------------------------------------------
// main_kernel v11 = v7 VERBATIM -- the converged vertex after 10 rounds:
// full-resident A (70.6 KB LDS, 2 blocks/CU), 2-pass acc-32, setprio around
// MFMA bursts, sim-column prefetch. The design-space ledger that pins this:
//  - 6 waves/SIMD (v2/v3): 85-reg budget < acc+arch -> spill, structural.
//  - more acc / fat waves (v5/v6): spill at 4 w/SIMD; TLP loss at 2 w/SIMD.
//  - M=128 batch-pair (v8): losing the 2nd co-resident block costs more
//    than B-reuse gains (209us).
//  - deeper prefetch (v4 +32 regs, v9 +16 regs): spill -- v7 is FLUSH
//    against the 128-reg/wave cap. Do not add live state anywhere.
//  - tail rebalance (v10): neutral; half2-mix (this version) marginally
//    better LDS read efficiency.
// Pass 1 = FIFO-ordered stage-ahead-2 pipeline. Pass 2 = 2-deep register
// double-buffered B. Tail: ALL waves compute softmax redundantly into
// per-wave attn copies (intra-wave DS ordering -> no final barrier).
__global__ __launch_bounds__(512, 4) void main_kernel(
    const float* __restrict__ neighbors, const float* __restrict__ stats,
    const half_t* __restrict__ Wns, const float* __restrict__ qcb,
    const float* __restrict__ sw2, const float* __restrict__ sb2,
    const float* __restrict__ alpha, float* __restrict__ attn_out,
    half_t* __restrict__ mixed) {
    __shared__ __align__(16) half_t A[64 * AS];  // 70656 B
    __shared__ float Llds[64][17];
    __shared__ float attn_s[8][64];              // per-wave copy: no tail barrier

    int b = blockIdx.x;
    int tid = threadIdx.x;
    const float* nb = neighbors + (size_t)b * NK * NE;
    const float* st = stats + (size_t)b * NK * NS;

    int r0 = tid >> 5;     // 0..15 (staging rows r0+16i)
    int c4 = tid & 31;     // float4-col within 128-col chunk
    int w = tid >> 6;      // wave 0..7
    int l = tid & 63, ln = l & 31, hi = l >> 5;
    const half_t* Abase = A + ln * AS + 8 * hi;
    const half_t* Wb = Wns + ((size_t)(w * 32 + ln)) * 16 + 8 * hi;  // + t*8192

    // ---- prologue: stage chunk 0; issue chunk 1; preload epilogue scalars;
    //      prefetch softmax sim column into the Llds pad col ----
    float4 s0, s1, s2, s3, sst;
    float qv1, w21, qv2, w22;
    {
        float4 p0 = *(const float4*)(nb + (size_t)(r0) * NE + 4 * c4);
        float4 p1 = *(const float4*)(nb + (size_t)(r0 + 16) * NE + 4 * c4);
        float4 p2 = *(const float4*)(nb + (size_t)(r0 + 32) * NE + 4 * c4);
        float4 p3 = *(const float4*)(nb + (size_t)(r0 + 48) * NE + 4 * c4);
        __builtin_amdgcn_sched_barrier(0);
        s0 = *(const float4*)(nb + (size_t)(r0) * NE + 128 + 4 * c4);
        s1 = *(const float4*)(nb + (size_t)(r0 + 16) * NE + 128 + 4 * c4);
        s2 = *(const float4*)(nb + (size_t)(r0 + 32) * NE + 128 + 4 * c4);
        s3 = *(const float4*)(nb + (size_t)(r0 + 48) * NE + 128 + 4 * c4);
        qv1 = qcb[(size_t)b * NE + w * 32 + ln];
        w21 = sw2[w * 32 + ln];
        qv2 = qcb[(size_t)b * NE + 256 + w * 32 + ln];
        w22 = sw2[256 + w * 32 + ln];
        __builtin_amdgcn_sched_barrier(0);
        *(half4_t*)&A[(r0) * AS + 4 * c4] = cvt4(p0);
        *(half4_t*)&A[(r0 + 16) * AS + 4 * c4] = cvt4(p1);
        *(half4_t*)&A[(r0 + 32) * AS + 4 * c4] = cvt4(p2);
        *(half4_t*)&A[(r0 + 48) * AS + 4 * c4] = cvt4(p3);
        // softmax sim column -> unused Llds pad col (read after final barrier)
        if (tid < 64) Llds[tid][16] = st[tid * NS + (NS - 1)];
    }
    asm volatile("s_waitcnt lgkmcnt(0)" ::: "memory");
    __builtin_amdgcn_sched_barrier(0);
    __builtin_amdgcn_s_barrier();
    __builtin_amdgcn_sched_barrier(0);

    floatx16 acc0 = {0,0,0,0,0,0,0,0,0,0,0,0,0,0,0,0};
    floatx16 acc1 = {0,0,0,0,0,0,0,0,0,0,0,0,0,0,0,0};

    // ---- pass 1, pipelined chunks 0..3 (8 K-steps of 16 each) ----
#pragma unroll 1
    for (int ch = 0; ch < 4; ++ch) {
        half8_t bfr[8];
#pragma unroll
        for (int s8 = 0; s8 < 8; ++s8)
            bfr[s8] = *(const half8_t*)(Wb + (size_t)(ch * 8 + s8) * 8192);
        __builtin_amdgcn_sched_barrier(0);
        float4 n0, n1, n2, n3;
        if (ch < 2) {
            n0 = *(const float4*)(nb + (size_t)(r0) * NE + (ch + 2) * 128 + 4 * c4);
            n1 = *(const float4*)(nb + (size_t)(r0 + 16) * NE + (ch + 2) * 128 + 4 * c4);
            n2 = *(const float4*)(nb + (size_t)(r0 + 32) * NE + (ch + 2) * 128 + 4 * c4);
            n3 = *(const float4*)(nb + (size_t)(r0 + 48) * NE + (ch + 2) * 128 + 4 * c4);
        } else if (ch == 2) {
            if (tid < 256)
                sst = *(const float4*)(st + (tid >> 2) * NS + (tid & 3) * 4);
        }
        __builtin_amdgcn_sched_barrier(0);
        __builtin_amdgcn_s_setprio(1);
#pragma unroll
        for (int s8 = 0; s8 < 8; ++s8) {
            int col = ch * 128 + s8 * 16;
            half8_t a0 = *(const half8_t*)&Abase[col];
            half8_t a1 = *(const half8_t*)&Abase[32 * AS + col];
            acc0 = __builtin_amdgcn_mfma_f32_32x32x16_f16(a0, bfr[s8], acc0, 0, 0, 0);
            acc1 = __builtin_amdgcn_mfma_f32_32x32x16_f16(a1, bfr[s8], acc1, 0, 0, 0);
        }
        __builtin_amdgcn_s_setprio(0);
        if (ch < 3) {
            *(half4_t*)&A[(r0) * AS + (ch + 1) * 128 + 4 * c4] = cvt4(s0);
            *(half4_t*)&A[(r0 + 16) * AS + (ch + 1) * 128 + 4 * c4] = cvt4(s1);
            *(half4_t*)&A[(r0 + 32) * AS + (ch + 1) * 128 + 4 * c4] = cvt4(s2);
            *(half4_t*)&A[(r0 + 48) * AS + (ch + 1) * 128 + 4 * c4] = cvt4(s3);
            s0 = n0; s1 = n1; s2 = n2; s3 = n3;
        } else {
            if (tid < 256)
                *(half4_t*)&A[(tid >> 2) * AS + 512 + (tid & 3) * 4] = cvt4(sst);
        }
        asm volatile("s_waitcnt lgkmcnt(0)" ::: "memory");
        __builtin_amdgcn_sched_barrier(0);
        __builtin_amdgcn_s_barrier();
        __builtin_amdgcn_sched_barrier(0);
    }
    // final K-step of pass 1 (stats cols 512..527, t = 32)
    {
        half8_t bfa = *(const half8_t*)(Wb + (size_t)32 * 8192);
        half8_t a0 = *(const half8_t*)&Abase[512];
        half8_t a1 = *(const half8_t*)&Abase[32 * AS + 512];
        __builtin_amdgcn_s_setprio(1);
        acc0 = __builtin_amdgcn_mfma_f32_32x32x16_f16(a0, bfa, acc0, 0, 0, 0);
        acc1 = __builtin_amdgcn_mfma_f32_32x32x16_f16(a1, bfa, acc1, 0, 0, 0);
        __builtin_amdgcn_s_setprio(0);
    }

    // ---- prime pass-2 first two B pairs (latency hides under epilogue-1) ----
    const half_t* Wb2 = Wb + 4096;  // cols +256
    half8_t pA0 = *(const half8_t*)(Wb2);
    half8_t pB0 = *(const half8_t*)(Wb2 + 8192);
    half8_t pA1 = *(const half8_t*)(Wb2 + 2 * 8192);
    half8_t pB1 = *(const half8_t*)(Wb2 + 3 * 8192);
    __builtin_amdgcn_sched_barrier(0);

    // ---- epilogue pass 1 ----
    {
        float g0[16], g1[16];
#pragma unroll
        for (int r = 0; r < 16; ++r) {
            g0[r] = gelu_erf(acc0[r] + qv1) * w21;
            g1[r] = gelu_erf(acc1[r] + qv1) * w21;
        }
        float rA = colreduce16(g0, ln);
        float rB = colreduce16(g1, ln);
        if (ln < 16) {
            int row = (ln & 3) + 8 * (ln >> 2) + 4 * hi;
            Llds[row][w] = rA;
            Llds[32 + row][w] = rB;
        }
    }

    // ---- pass 2: cols 256..511 over k 0..527, 2-deep double-buffered B ----
    acc0 = (floatx16){0,0,0,0,0,0,0,0,0,0,0,0,0,0,0,0};
    acc1 = (floatx16){0,0,0,0,0,0,0,0,0,0,0,0,0,0,0,0};
#pragma unroll 1
    for (int t2 = 0; t2 < 16; ++t2) {
        int tn = 2 * t2 + 4;
        if (tn > 32) tn = 32;
        int tn1 = tn + 1;
        if (tn1 > 32) tn1 = 32;   // never touch t=33 (doesn't exist)
        half8_t nA = *(const half8_t*)(Wb2 + (size_t)tn * 8192);
        half8_t nB = *(const half8_t*)(Wb2 + (size_t)tn1 * 8192);
        int col = t2 * 32;
        half8_t a0 = *(const half8_t*)&Abase[col];
        half8_t a1 = *(const half8_t*)&Abase[32 * AS + col];
        __builtin_amdgcn_s_setprio(1);
        acc0 = __builtin_amdgcn_mfma_f32_32x32x16_f16(a0, pA0, acc0, 0, 0, 0);
        acc1 = __builtin_amdgcn_mfma_f32_32x32x16_f16(a1, pA0, acc1, 0, 0, 0);
        half8_t a0b = *(const half8_t*)&Abase[col + 16];
        half8_t a1b = *(const half8_t*)&Abase[32 * AS + col + 16];
        acc0 = __builtin_amdgcn_mfma_f32_32x32x16_f16(a0b, pB0, acc0, 0, 0, 0);
        acc1 = __builtin_amdgcn_mfma_f32_32x32x16_f16(a1b, pB0, acc1, 0, 0, 0);
        __builtin_amdgcn_s_setprio(0);
        pA0 = pA1; pB0 = pB1; pA1 = nA; pB1 = nB;
    }
    // pass-2 K-tail: stats cols 512..527 (t = 32, now in pA0)
    {
        half8_t a0 = *(const half8_t*)&Abase[512];
        half8_t a1 = *(const half8_t*)&Abase[32 * AS + 512];
        __builtin_amdgcn_s_setprio(1);
        acc0 = __builtin_amdgcn_mfma_f32_32x32x16_f16(a0, pA0, acc0, 0, 0, 0);
        acc1 = __builtin_amdgcn_mfma_f32_32x32x16_f16(a1, pA0, acc1, 0, 0, 0);
        __builtin_amdgcn_s_setprio(0);
    }

    // ---- epilogue pass 2 ----
    {
        float g0[16], g1[16];
#pragma unroll
        for (int r = 0; r < 16; ++r) {
            g0[r] = gelu_erf(acc0[r] + qv2) * w22;
            g1[r] = gelu_erf(acc1[r] + qv2) * w22;
        }
        float rA = colreduce16(g0, ln);
        float rB = colreduce16(g1, ln);
        if (ln < 16) {
            int row = (ln & 3) + 8 * (ln >> 2) + 4 * hi;
            Llds[row][8 + w] = rA;
            Llds[32 + row][8 + w] = rB;
        }
    }
    __syncthreads();   // Llds is cross-wave: barrier required

    // ---- softmax over K=64: ALL waves redundantly; lane l owns k=l ----
    {
        int k = l;
        float lsum = 0.0f;
#pragma unroll
        for (int j = 0; j < 16; ++j) lsum += Llds[k][j];
        float sim = Llds[k][16];   // prefetched at prologue
        float logit = lsum + sb2[0] + alpha[0] * sim;
        float mx = logit;
#pragma unroll
        for (int m = 1; m < 64; m <<= 1) mx = fmaxf(mx, __shfl_xor(mx, m, 64));
        float e = __expf(logit - mx);
        float s = e;
#pragma unroll
        for (int m = 1; m < 64; m <<= 1) s += __shfl_xor(s, m, 64);
        float at = e / s;
        attn_s[w][k] = at;                 // own wave's copy: DS in-order
        if (w == 0) attn_out[(size_t)b * NK + k] = at;
    }
    // NO barrier: each wave reads only its own attn_s[w] copy below.

    // ---- mix from LDS (half2 per thread): mixed[e'] = sum_k attn[k]*A[k][e'] ----
    if (tid < 264) {
        int c0 = 2 * tid;  // cols [c0, c0+1], covers 0..527 (real data only)
        float m0 = 0.0f, m1 = 0.0f;
#pragma unroll 8
        for (int k = 0; k < NK; ++k) {
            half2_t v = *(const half2_t*)&A[k * AS + c0];
            float aw = attn_s[w][k];
            m0 += aw * (float)v[0];
            m1 += aw * (float)v[1];
        }
        *(half2_t*)&mixed[(size_t)b * AS + c0] = (half2_t){(half_t)m0, (half_t)m1};
    } else if (tid < 270) {
        int z = tid - 264;  // zero cols 528..551 (6 x half4)
        half4_t hz = {};
        *(half4_t*)&mixed[(size_t)b * AS + 528 + 4 * z] = hz;
    }
}

// ---------------------------------------------------------------------------
// proj_kernel: out = gelu(mixed@pw1 + pb1) @ pw2 + pb2, both layers fused.
// 1024 threads = 16 waves (wave owns 32 cols) for better latency hiding.
__global__ __launch_bounds__(1024) void proj_kernel(
    const half_t* __restrict__ mixedp, const half_t* __restrict__ Wp1,
    const half_t* __restrict__ Wp2, const float* __restrict__ pb1,
    const float* __restrict__ pb2, float* __restrict__ out) {
    constexpr int AS3 = AS;
    __shared__ __align__(16) half_t A1[16 * AS3];
    int b0 = blockIdx.x * 16;
    int tid = threadIdx.x;
    const uint4* src = (const uint4*)(mixedp + (size_t)b0 * AS3);
    for (int i = tid; i < 1104; i += 1024) ((uint4*)A1)[i] = src[i];
    __syncthreads();

    int w = tid >> 6, l = tid & 63, lg = l >> 4, ln = l & 15;
    floatx4 acc[2] = { {0,0,0,0}, {0,0,0,0} };
    for (int t = 0; t < 17; ++t) {
        half8_t a = *(const half8_t*)&A1[ln * AS3 + t * 32 + 8 * lg];
#pragma unroll
        for (int ni = 0; ni < 2; ++ni) {
            int n = w * 32 + ni * 16 + ln;
            half8_t bf = *(const half8_t*)(Wp1 + ((size_t)t * NE + n) * 32 + 8 * lg);
            acc[ni] = __builtin_amdgcn_mfma_f32_16x16x32_f16(a, bf, acc[ni], 0, 0, 0);
        }
    }
    __syncthreads();
#pragma unroll
    for (int ni = 0; ni < 2; ++ni) {
        int col = w * 32 + ni * 16 + ln;
        float bias = pb1[col];
#pragma unroll
        for (int r = 0; r < 4; ++r) {
            int row = 4 * lg + r;
            A1[row * AS3 + col] = (half_t)gelu_erf(acc[ni][r] + bias);
        }
    }
    __syncthreads();
    floatx4 acc2[2] = { {0,0,0,0}, {0,0,0,0} };
    for (int t = 0; t < 16; ++t) {
        half8_t a = *(const half8_t*)&A1[ln * AS3 + t * 32 + 8 * lg];
#pragma unroll
        for (int ni = 0; ni < 2; ++ni) {
            int n = w * 32 + ni * 16 + ln;
            half8_t bf = *(const half8_t*)(Wp2 + ((size_t)t * NE + n) * 32 + 8 * lg);
            acc2[ni] = __builtin_amdgcn_mfma_f32_16x16x32_f16(a, bf, acc2[ni], 0, 0, 0);
        }
    }
#pragma unroll
    for (int ni = 0; ni < 2; ++ni) {
        int col = w * 32 + ni * 16 + ln;
        float bias = pb2[col];
#pragma unroll
        for (int r = 0; r < 4; ++r)
            out[(size_t)(b0 + 4 * lg + r) * NE + col] = acc2[ni][r] + bias;
    }
}

// ---------------------------------------------------------------------------
extern "C" void kernel_launch(void* const* d_in, const int* in_sizes, int n_in,
                              void* d_out, int out_size, void* d_ws, size_t ws_size,
                              hipStream_t stream) {
    (void)in_sizes; (void)n_in; (void)out_size; (void)ws_size;
    const float* q     = (const float*)d_in[0];
    const float* c     = (const float*)d_in[1];
    const float* nb    = (const float*)d_in[2];
    const float* st    = (const float*)d_in[3];
    const float* sw1   = (const float*)d_in[4];
    const float* sb1   = (const float*)d_in[5];
    const float* sw2   = (const float*)d_in[6];
    const float* sb2   = (const float*)d_in[7];
    const float* alpha = (const float*)d_in[8];
    const float* pw1   = (const float*)d_in[9];
    const float* pb1   = (const float*)d_in[10];
    const float* pw2   = (const float*)d_in[11];
    const float* pb2   = (const float*)d_in[12];

    char* ws = (char*)d_ws;
    half_t* Wq  = (half_t*)(ws + 0);          // 1024*512*2 = 1048576
    half_t* Wns = (half_t*)(ws + 1048576);    // 33*512*16*2 = 540672
    half_t* Wp1 = (half_t*)(ws + 1605632);    // 544*512*2  = 557056
    half_t* Wp2 = (half_t*)(ws + 2162688);    // 512*512*2  = 524288
    float*  qcb = (float*)(ws + 2686976);     // 2048*512*4 = 4194304
    half_t* mix = (half_t*)(ws + 6881280);    // 2048*552*2 = 2260992

    float* outp  = (float*)d_out;
    float* attnp = outp + (size_t)NBATCH * NE;

    pack_all<<<784, 256, 0, stream>>>(sw1, pw1, pw2, Wq, Wns, Wp1, Wp2);
    qc_kernel<<<256, 512, 0, stream>>>(q, c, Wq, sb1, qcb);
    main_kernel<<<2048, 512, 0, stream>>>(nb, st, Wns, qcb, sw2, sb2, alpha, attnp, mix);
    proj_kernel<<<128, 1024, 0, stream>>>(mix, Wp1, Wp2, pb1, pb2, outp);
}